// Round 4
// baseline (805.239 us; speedup 1.0000x reference)
//
#include <hip/hip_runtime.h>
#include <stdint.h>
#include <math.h>

#define NN 128
#define EE 256
#define HH 256

#define OFF_LOGP 0
#define OFF_IDX  32768
#define OFF_INIT 65536
#define OFF_LAST 66048
#define OFF_RS   66560

// keys row stride in floats / float4 slots (padded: 260 = 65*4)
#define KST  260
#define KST4 65

__device__ __forceinline__ uint32_t rotl32_(uint32_t x, int d){ return (x<<d)|(x>>(32-d)); }

// Threefry-2x32, 20 rounds, JAX key schedule (bit-identical to rounds 1-3)
__device__ __forceinline__ void tf2x32(uint32_t k0, uint32_t k1, uint32_t x0, uint32_t x1,
                                       uint32_t& o0, uint32_t& o1){
  uint32_t k2 = k0 ^ k1 ^ 0x1BD11BDAu;
  x0 += k0; x1 += k1;
#define TF_RND(r) { x0 += x1; x1 = rotl32_(x1,(r)); x1 ^= x0; }
  TF_RND(13) TF_RND(15) TF_RND(26) TF_RND(6)
  x0 += k1; x1 += k2 + 1u;
  TF_RND(17) TF_RND(29) TF_RND(16) TF_RND(24)
  x0 += k2; x1 += k0 + 2u;
  TF_RND(13) TF_RND(15) TF_RND(26) TF_RND(6)
  x0 += k0; x1 += k1 + 3u;
  TF_RND(17) TF_RND(29) TF_RND(16) TF_RND(24)
  x0 += k1; x1 += k2 + 4u;
  TF_RND(13) TF_RND(15) TF_RND(26) TF_RND(6)
  x0 += k2; x1 += k0 + 5u;
#undef TF_RND
  o0 = x0; o1 = x1;
}

// Fast tanh via hardware exp2: tanh(x) = sign(x) * (1-E)/(1+E), E = e^{-2|x|}.
// Division refined to ~0.5 ulp (NR + residual); exp2 HW ~1 ulp => abs err ~1e-7,
// same perturbation class as the round-3 NR-div change. Saturates naturally.
__device__ __forceinline__ float fast_tanhf(float x){
  float ax = __builtin_fabsf(x);
  float E = __builtin_amdgcn_exp2f(ax * -2.885390081777927f);  // 2^(-2*log2(e)*|x|)
  float num = 1.0f - E;
  float den = 1.0f + E;
  float inv = __builtin_amdgcn_rcpf(den);
  inv = fmaf(fmaf(-den, inv, 1.0f), inv, inv);   // Newton refine
  float r = num * inv;
  r = fmaf(fmaf(-den, r, num), inv, r);          // residual correction
  return __builtin_copysignf(r, x);
}

// jax.random.gumbel element (partitionable threefry) — bit-identical to rounds 1-3.
// Uses IEEE logf: do NOT touch (feeds argmax directly).
__device__ __forceinline__ float jax_gumbel(uint32_t k0, uint32_t k1, uint32_t t){
  uint32_t o0, o1, bits;
  tf2x32(k0, k1, 0u, t, o0, o1);
  bits = o0 ^ o1;
  float u = __uint_as_float((bits >> 9) | 0x3f800000u) - 1.0f;
  const float kTiny = 1.17549435e-38f;
  u = fmaxf(kTiny, u + kTiny);
  return -logf(-logf(u));
}

// ---------------- small precompute kernels ----------------
__global__ void k_tmp1(const float* __restrict__ liw, const float* __restrict__ Wr,
                       float* __restrict__ tmp1){
  int e = threadIdx.x;
  float acc = 0.f;
  for (int k = 0; k < 2*EE; ++k) acc = fmaf(liw[k], Wr[(size_t)k*EE + e], acc);
  tmp1[e] = acc;
}

__global__ void k_T1(const float* __restrict__ Wr, const float* __restrict__ Wq,
                     float* __restrict__ T1){
  int r = blockIdx.x, h = threadIdx.x;
  float acc = 0.f;
  for (int e = 0; e < EE; ++e) acc = fmaf(Wr[(size_t)r*EE + e], Wq[(size_t)e*HH + h], acc);
  T1[(size_t)r*HH + h] = acc;
}

__global__ void k_base(const float* __restrict__ lcv, const float* __restrict__ Whbar,
                       const float* __restrict__ bhbar, const float* __restrict__ brest,
                       const float* __restrict__ Wq, const float* __restrict__ bq,
                       float* __restrict__ base){
  __shared__ float sm[EE];
  __shared__ float hb2[EE];
  int b = blockIdx.x, t = threadIdx.x;
  float acc = 0.f;
  const float* p = lcv + (size_t)b*NN*EE + t;
  for (int n = 0; n < NN; ++n) acc += p[(size_t)n*EE];
  sm[t] = acc * 0.0078125f;
  __syncthreads();
  float a2 = 0.f;
  for (int e = 0; e < EE; ++e) a2 = fmaf(sm[e], Whbar[(size_t)e*EE + t], a2);
  hb2[t] = (a2 + bhbar[t]) + brest[t];
  __syncthreads();
  float a3 = 0.f;
  for (int e = 0; e < EE; ++e) a3 = fmaf(hb2[e], Wq[(size_t)e*HH + t], a3);
  base[(size_t)b*HH + t] = a3 + bq[t];
}

// ---------------- main sequential decoder: 1 block per batch, 1024 threads ----------------
__global__ __launch_bounds__(1024, 4) void dec_main(
    const float* __restrict__ lcv, const float* __restrict__ onode,
    const int* __restrict__ mask_in, const int* __restrict__ id_in,
    const float* __restrict__ Wk, const float* __restrict__ bk,
    const float* __restrict__ vvec, const float* __restrict__ T1,
    const float* __restrict__ base, const float* __restrict__ tmp1,
    const float* __restrict__ Wq, float* __restrict__ out)
{
  const int b = blockIdx.x;
  const int tid = threadIdx.x;
  const int wid = tid >> 6;
  const int lane = tid & 63;

  __shared__ __align__(16) float keys_lds[NN*KST];   // 133120 B; init staging aliases inside
  __shared__ __align__(16) float q_s[272];           // padded: group stride 68 floats
  __shared__ __align__(16) float base_s[HH];
  __shared__ __align__(16) float p1row[HH];
  __shared__ __align__(16) float2 on_s[NN];          // original_node rows (LDS copy)
  __shared__ float u_s[NN];
  __shared__ float g2_s[2][NN];                      // double-buffered gumbel rows
  __shared__ int act_s[NN];
  __shared__ int pos_s[NN];
  __shared__ int mask_s[NN];
  __shared__ uint32_t sk0[NN], sk1[NN];
  __shared__ int idx_sh, L_sh;

  const float NEG_INF = -__builtin_huge_valf();
  const int id0 = id_in[0];

  // ---- init GEMM: keys[b] -> LDS, P2[b]=lcv[b]@T1b -> regs ----
  // wave wid owns j-rows wid*8..wid*8+7; lane owns h = lane*4..+3.
  // e-accumulation order 0..255 sequential fmaf => bit-identical to rounds 1-3.
  float4 kacc[8], p2acc[8];
  #pragma unroll
  for (int r = 0; r < 8; ++r){
    kacc[r]  = make_float4(0.f,0.f,0.f,0.f);
    p2acc[r] = make_float4(0.f,0.f,0.f,0.f);
  }
  {
    float* sA = keys_lds;            // [128][36] padded A-chunk
    float* sW = keys_lds + 4608;     // [32][256] Wk chunk
    float* sT = keys_lds + 12800;    // [32][256] T1b chunk
    for (int ch = 0; ch < 8; ++ch){
      const int e0 = ch << 5;
      __syncthreads();
      { // stage lcv chunk: 128 rows x 32e (padded stride 36)
        const int r = tid >> 3, c = tid & 7;
        const float4 t = ((const float4*)(lcv + ((size_t)b*NN + r)*EE + e0))[c];
        ((float4*)sA)[r*9 + c] = t;
      }
      #pragma unroll
      for (int s = 0; s < 2; ++s){ // stage Wk / T1b chunks (32e x 256h each)
        const int idx4 = s*1024 + tid;
        const int e = idx4 >> 6, c = idx4 & 63;
        ((float4*)sW)[idx4] = ((const float4*)(Wk + (size_t)(e0+e)*HH))[c];
        ((float4*)sT)[idx4] = ((const float4*)(T1 + (size_t)(EE+e0+e)*HH))[c];
      }
      __syncthreads();
      const float* aRow = sA + (wid << 3)*36;
      for (int e = 0; e < 32; ++e){
        const float4 wv = ((const float4*)sW)[(e<<6) + lane];  // conflict-free
        const float4 tv = ((const float4*)sT)[(e<<6) + lane];
        #pragma unroll
        for (int r = 0; r < 8; ++r){
          const float av = aRow[r*36 + e];                     // wave-broadcast
          kacc[r].x = fmaf(av, wv.x, kacc[r].x);
          kacc[r].y = fmaf(av, wv.y, kacc[r].y);
          kacc[r].z = fmaf(av, wv.z, kacc[r].z);
          kacc[r].w = fmaf(av, wv.w, kacc[r].w);
          p2acc[r].x = fmaf(av, tv.x, p2acc[r].x);
          p2acc[r].y = fmaf(av, tv.y, p2acc[r].y);
          p2acc[r].z = fmaf(av, tv.z, p2acc[r].z);
          p2acc[r].w = fmaf(av, tv.w, p2acc[r].w);
        }
      }
    }
  }
  __syncthreads();   // staging reads done everywhere -> safe to overwrite region with keys
  {
    const float4 bkv = ((const float4*)bk)[lane];
    // swizzled slot: phys = gh*16 + (c ^ gh), gh = lane>>4, c = lane&15
    const int sphys = ((lane >> 4) << 4) | ((lane & 15) ^ (lane >> 4));
    #pragma unroll
    for (int r = 0; r < 8; ++r){
      const int j = (wid << 3) + r;
      float4 kv = kacc[r];
      kv.x += bkv.x; kv.y += bkv.y; kv.z += bkv.z; kv.w += bkv.w;
      ((float4*)keys_lds)[j*KST4 + sphys] = kv;
    }
  }

  const int grp = tid & 3;       // h-group (h base = grp*64)
  const int aslot = tid >> 2;    // active-list slot handled by this thread

  // v in registers (kacc dead now -> VGPR headroom)
  float4 vreg[16];
  #pragma unroll
  for (int c = 0; c < 16; ++c) vreg[c] = ((const float4*)vvec)[(grp << 4) + c];

  // ---- other shared init ----
  if (tid < HH){
    const float bs = base[(size_t)b*HH + tid];
    base_s[tid] = bs;
    // c0 = tmp1 @ Wq (same order as old k_c0: e 0..255 sequential fmaf)
    float c0v = 0.f;
    for (int e = 0; e < EE; ++e) c0v = fmaf(tmp1[e], Wq[(size_t)e*HH + tid], c0v);
    q_s[(tid>>6)*68 + (tid&63)] = bs + c0v;   // query0
  } else if (tid < HH + NN){
    const int j = tid - HH;
    mask_s[j] = mask_in[(size_t)b*NN + j];
    uint32_t o0,o1; tf2x32(0u, 42u, 0u, (uint32_t)j, o0, o1);
    sk0[j] = o0; sk1[j] = o1;
  } else if (tid == HH + NN){
    out[OFF_INIT + 2*b]     = onode[(size_t)b*NN*2 + 0];
    out[OFF_INIT + 2*b + 1] = onode[(size_t)b*NN*2 + 1];
  } else if (tid >= 512 && tid < 512 + NN){
    on_s[tid - 512] = ((const float2*)onode)[b*NN + (tid - 512)];
  }
  __syncthreads();
  if (tid == 0){
    int L = 0;
    for (int j = 0; j < NN; ++j){
      if (mask_s[j] == 0){ act_s[L] = j; pos_s[j] = L; ++L; }
    }
    L_sh = L;
  }
  if (wid == 15){  // gumbel row for step 0
    g2_s[0][lane]      = jax_gumbel(sk0[0], sk1[0], (uint32_t)(b*NN + lane));
    g2_s[0][64 + lane] = jax_gumbel(sk0[0], sk1[0], (uint32_t)(b*NN + 64 + lane));
  }

  int cur = 0;   // meaningful on wave0 lane0 only

  // ---- sequential steps ----
  for (int i = 0; i < NN; ++i){
    __syncthreads();                       // A: protects q_s / u_s / act_s
    const int L = L_sh;
    // phase U: u[j] for ACTIVE j only (4 lanes per j, 64 sequential h per lane).
    // tanh values into th[16] blocks (ILP); accumulator chain in original order.
    if (aslot < L){
      const int j = act_s[aslot];
      const int kb4 = j*KST4 + (grp << 4);
      const int qb4 = grp*17;
      float s = 0.f;
      #pragma unroll
      for (int c4 = 0; c4 < 4; ++c4){
        float th[16];
        #pragma unroll
        for (int cc = 0; cc < 4; ++cc){
          const int c = c4*4 + cc;
          const float4 kv = ((const float4*)keys_lds)[kb4 + (c ^ grp)];
          const float4 qv = ((const float4*)q_s)[qb4 + c];
          th[4*cc+0] = fast_tanhf(kv.x + qv.x);
          th[4*cc+1] = fast_tanhf(kv.y + qv.y);
          th[4*cc+2] = fast_tanhf(kv.z + qv.z);
          th[4*cc+3] = fast_tanhf(kv.w + qv.w);
        }
        #pragma unroll
        for (int cc = 0; cc < 4; ++cc){
          const float4 vv = vreg[c4*4 + cc];
          s = fmaf(th[4*cc+0], vv.x, s);
          s = fmaf(th[4*cc+1], vv.y, s);
          s = fmaf(th[4*cc+2], vv.z, s);
          s = fmaf(th[4*cc+3], vv.w, s);
        }
      }
      s += __shfl_xor(s, 1);   // (g0+g1), (g2+g3)
      s += __shfl_xor(s, 2);   // ((g0+g1)+(g2+g3)) — same bracketing as rounds 1-3
      if (grp == 0) u_s[j] = s;
    } else if (wid == 15 && i + 1 < NN){
      // wave 15 never active in U (aslot >= 240): precompute next step's gumbels
      const int nb = (i + 1) & 1;
      g2_s[nb][lane]      = jax_gumbel(sk0[i+1], sk1[i+1], (uint32_t)(b*NN + lane));
      g2_s[nb][64 + lane] = jax_gumbel(sk0[i+1], sk1[i+1], (uint32_t)(b*NN + 64 + lane));
    }
    __syncthreads();                       // B: u_s ready
    // phase S-core (wave 0): argmax only; publish idx ASAP
    float l0 = 0.f, l1 = 0.f; int bi = 0;
    if (wid == 0){
      l0 = 10.0f * fast_tanhf(u_s[lane]);
      l1 = 10.0f * fast_tanhf(u_s[64 + lane]);
      if (mask_s[lane])      l0 = NEG_INF;
      if (mask_s[64 + lane]) l1 = NEG_INF;
      const float y0 = l0 + g2_s[i & 1][lane];
      const float y1 = l1 + g2_s[i & 1][64 + lane];
      float bv;
      if (y1 > y0){ bv = y1; bi = 64 + lane; } else { bv = y0; bi = lane; }
      #pragma unroll
      for (int off = 1; off < 64; off <<= 1){
        const float ov = __shfl_xor(bv, off);
        const int   oi = __shfl_xor(bi, off);
        if (ov > bv || (ov == bv && oi < bi)){ bv = ov; bi = oi; }
      }
      if (i == 0 && id0 == 0) bi = 0;
      if (lane == 0) idx_sh = bi;
    }
    __syncthreads();                       // C: idx published
    const int idx = idx_sh;
    // phase P1 (step 0 only): p1row = lcv[b, idx0] @ T1[:E]
    if (i == 0){
      if (tid < HH){
        const float* arow = lcv + ((size_t)b*NN + idx)*EE;
        float acc = 0.f;
        for (int e = 0; e < EE; ++e) acc = fmaf(arow[e], T1[(size_t)e*HH + tid], acc);
        p1row[tid] = acc;
      }
      __syncthreads();
    }
    // phase Q (owner wave) runs IN PARALLEL with wave0's logp/output tail
    if (wid == (idx >> 3)){
      const int r2 = idx & 7;
      float4 pp;
      switch (r2){
        case 0: pp = p2acc[0]; break;
        case 1: pp = p2acc[1]; break;
        case 2: pp = p2acc[2]; break;
        case 3: pp = p2acc[3]; break;
        case 4: pp = p2acc[4]; break;
        case 5: pp = p2acc[5]; break;
        case 6: pp = p2acc[6]; break;
        default: pp = p2acc[7]; break;
      }
      const float4 b4 = ((const float4*)base_s)[lane];
      const float4 p4 = ((const float4*)p1row)[lane];
      float4 nq;
      nq.x = (b4.x + p4.x) + pp.x;
      nq.y = (b4.y + p4.y) + pp.y;
      nq.z = (b4.z + p4.z) + pp.z;
      nq.w = (b4.w + p4.w) + pp.w;
      ((float4*)q_s)[((lane >> 4)*17) + (lane & 15)] = nq;
    }
    if (wid == 0){
      // deferred logp + outputs + act-list update (off the inter-wave critical path)
      float es = __expf(l0) + __expf(l1);   // logits bounded by ±10 (logp-only path)
      #pragma unroll
      for (int off = 1; off < 64; off <<= 1) es += __shfl_xor(es, off);
      const float lown = (bi >= 64) ? l1 : l0;
      const float lsel = __shfl(lown, bi & 63);
      const float logp = lsel - __logf(es);
      if (lane == 0){
        out[OFF_LOGP + b*NN + i] = logp;
        out[OFF_IDX  + b*NN + i] = (float)bi;
        const float2 pc = on_s[cur];
        const float2 pn = on_s[bi];
        const float dx = pn.x - pc.x, dy = pn.y - pc.y;
        out[OFF_RS + b*NN + i] = sqrtf(dx*dx + dy*dy);
        if (i == NN-1){ out[OFF_LAST + 2*b] = pn.x; out[OFF_LAST + 2*b + 1] = pn.y; }
        cur = bi;
        if (mask_s[bi] == 0){
          mask_s[bi] = 1;
          const int p = pos_s[bi];
          const int Lm = L_sh - 1;
          const int last = act_s[Lm];
          act_s[p] = last;
          pos_s[last] = p;
          L_sh = Lm;
        }
      }
    }
  }
}

extern "C" void kernel_launch(void* const* d_in, const int* in_sizes, int n_in,
                              void* d_out, int out_size, void* d_ws, size_t ws_size,
                              hipStream_t stream){
  const float* lcv   = (const float*)d_in[0];
  const float* onode = (const float*)d_in[1];
  const int*   mask  = (const int*)d_in[2];
  const int*   id    = (const int*)d_in[3];
  const float* liw   = (const float*)d_in[4];
  const float* Whbar = (const float*)d_in[5];
  const float* bhbar = (const float*)d_in[6];
  const float* Wrest = (const float*)d_in[7];
  const float* brest = (const float*)d_in[8];
  const float* Wk    = (const float*)d_in[9];
  const float* bk    = (const float*)d_in[10];
  const float* Wq    = (const float*)d_in[11];
  const float* bq    = (const float*)d_in[12];
  const float* vv    = (const float*)d_in[13];

  float* ws   = (float*)d_ws;
  float* T1   = ws;            // 512*256
  float* base = ws + 131072;   // 256*256
  float* tmp1 = ws + 196608;   // 256
  float* out  = (float*)d_out;

  hipLaunchKernelGGL(k_tmp1, dim3(1),   dim3(256), 0, stream, liw, Wrest, tmp1);
  hipLaunchKernelGGL(k_T1,   dim3(512), dim3(256), 0, stream, Wrest, Wq, T1);
  hipLaunchKernelGGL(k_base, dim3(256), dim3(256), 0, stream, lcv, Whbar, bhbar, brest, Wq, bq, base);
  hipLaunchKernelGGL(dec_main, dim3(256), dim3(1024), 0, stream,
                     lcv, onode, mask, id, Wk, bk, vv, T1, base, tmp1, Wq, out);
}

// Round 5
// 620.006 us; speedup vs baseline: 1.2988x; 1.2988x over previous
//
#include <hip/hip_runtime.h>
#include <stdint.h>
#include <math.h>

#define NN 128
#define EE 256
#define HH 256

#define OFF_LOGP 0
#define OFF_IDX  32768
#define OFF_INIT 65536
#define OFF_LAST 66048
#define OFF_RS   66560

// keys row stride in floats / float4 slots (padded: 260 = 65*4) -- fallback path
#define KST  260
#define KST4 65

__device__ __forceinline__ uint32_t rotl32_(uint32_t x, int d){ return (x<<d)|(x>>(32-d)); }

// Threefry-2x32, 20 rounds, JAX key schedule (bit-identical to rounds 1-4)
__device__ __forceinline__ void tf2x32(uint32_t k0, uint32_t k1, uint32_t x0, uint32_t x1,
                                       uint32_t& o0, uint32_t& o1){
  uint32_t k2 = k0 ^ k1 ^ 0x1BD11BDAu;
  x0 += k0; x1 += k1;
#define TF_RND(r) { x0 += x1; x1 = rotl32_(x1,(r)); x1 ^= x0; }
  TF_RND(13) TF_RND(15) TF_RND(26) TF_RND(6)
  x0 += k1; x1 += k2 + 1u;
  TF_RND(17) TF_RND(29) TF_RND(16) TF_RND(24)
  x0 += k2; x1 += k0 + 2u;
  TF_RND(13) TF_RND(15) TF_RND(26) TF_RND(6)
  x0 += k0; x1 += k1 + 3u;
  TF_RND(17) TF_RND(29) TF_RND(16) TF_RND(24)
  x0 += k1; x1 += k2 + 4u;
  TF_RND(13) TF_RND(15) TF_RND(26) TF_RND(6)
  x0 += k2; x1 += k0 + 5u;
#undef TF_RND
  o0 = x0; o1 = x1;
}

// Fast tanh via hardware exp2 (same function as round-4, which passed)
__device__ __forceinline__ float fast_tanhf(float x){
  float ax = __builtin_fabsf(x);
  float E = __builtin_amdgcn_exp2f(ax * -2.885390081777927f);  // 2^(-2*log2(e)*|x|)
  float num = 1.0f - E;
  float den = 1.0f + E;
  float inv = __builtin_amdgcn_rcpf(den);
  inv = fmaf(fmaf(-den, inv, 1.0f), inv, inv);   // Newton refine
  float r = num * inv;
  r = fmaf(fmaf(-den, r, num), inv, r);          // residual correction
  return __builtin_copysignf(r, x);
}

// jax.random.gumbel element — bit-identical to rounds 1-4 (feeds argmax: IEEE logf)
__device__ __forceinline__ float jax_gumbel(uint32_t k0, uint32_t k1, uint32_t t){
  uint32_t o0, o1, bits;
  tf2x32(k0, k1, 0u, t, o0, o1);
  bits = o0 ^ o1;
  float u = __uint_as_float((bits >> 9) | 0x3f800000u) - 1.0f;
  const float kTiny = 1.17549435e-38f;
  u = fmaxf(kTiny, u + kTiny);
  return -logf(-logf(u));
}

// Wave-wide argmax(+sum) reduce: quad_perm xor1/xor2 + row_ror4/8 (DPP) +
// ds_swizzle xor16 + shfl xor32. Associative w/ smallest-index tie-break.
#define CMB_DPP(CTRL) { \
  float ny_ = __int_as_float(__builtin_amdgcn_mov_dpp(__float_as_int(y), (CTRL), 0xf, 0xf, false)); \
  int   nj_ = __builtin_amdgcn_mov_dpp(pj, (CTRL), 0xf, 0xf, false); \
  float ne_ = __int_as_float(__builtin_amdgcn_mov_dpp(__float_as_int(es), (CTRL), 0xf, 0xf, false)); \
  es += ne_; \
  if (ny_ > y || (ny_ == y && nj_ < pj)){ y = ny_; pj = nj_; } }
#define CMB_SWZ16() { \
  float ny_ = __int_as_float(__builtin_amdgcn_ds_swizzle(__float_as_int(y), 0x401F)); \
  int   nj_ = __builtin_amdgcn_ds_swizzle(pj, 0x401F); \
  float ne_ = __int_as_float(__builtin_amdgcn_ds_swizzle(__float_as_int(es), 0x401F)); \
  es += ne_; \
  if (ny_ > y || (ny_ == y && nj_ < pj)){ y = ny_; pj = nj_; } }
#define CMB_SHF32() { \
  float ny_ = __shfl_xor(y, 32); \
  int   nj_ = __shfl_xor(pj, 32); \
  float ne_ = __shfl_xor(es, 32); \
  es += ne_; \
  if (ny_ > y || (ny_ == y && nj_ < pj)){ y = ny_; pj = nj_; } }

// ---------------- small precompute kernels ----------------
__global__ void k_tmp1(const float* __restrict__ liw, const float* __restrict__ Wr,
                       float* __restrict__ tmp1){
  int e = threadIdx.x;
  float acc = 0.f;
  for (int k = 0; k < 2*EE; ++k) acc = fmaf(liw[k], Wr[(size_t)k*EE + e], acc);
  tmp1[e] = acc;
}

__global__ void k_c0(const float* __restrict__ tmp1, const float* __restrict__ Wq,
                     float* __restrict__ c0){
  int h = threadIdx.x;
  float acc = 0.f;
  for (int e = 0; e < EE; ++e) acc = fmaf(tmp1[e], Wq[(size_t)e*HH + h], acc);
  c0[h] = acc;
}

__global__ void k_T1(const float* __restrict__ Wr, const float* __restrict__ Wq,
                     float* __restrict__ T1){
  int r = blockIdx.x, h = threadIdx.x;
  float acc = 0.f;
  for (int e = 0; e < EE; ++e) acc = fmaf(Wr[(size_t)r*EE + e], Wq[(size_t)e*HH + h], acc);
  T1[(size_t)r*HH + h] = acc;
}

__global__ void k_base(const float* __restrict__ lcv, const float* __restrict__ Whbar,
                       const float* __restrict__ bhbar, const float* __restrict__ brest,
                       const float* __restrict__ Wq, const float* __restrict__ bq,
                       float* __restrict__ base){
  __shared__ float sm[EE];
  __shared__ float hb2[EE];
  int b = blockIdx.x, t = threadIdx.x;
  float acc = 0.f;
  const float* p = lcv + (size_t)b*NN*EE + t;
  for (int n = 0; n < NN; ++n) acc += p[(size_t)n*EE];
  sm[t] = acc * 0.0078125f;
  __syncthreads();
  float a2 = 0.f;
  for (int e = 0; e < EE; ++e) a2 = fmaf(sm[e], Whbar[(size_t)e*EE + t], a2);
  hb2[t] = (a2 + bhbar[t]) + brest[t];
  __syncthreads();
  float a3 = 0.f;
  for (int e = 0; e < EE; ++e) a3 = fmaf(hb2[e], Wq[(size_t)e*HH + t], a3);
  base[(size_t)b*HH + t] = a3 + bq[t];
}

// keys[b] = lcv[b]@Wk + bk ; P2[b] = lcv[b]@T1b — port of the verified round-2
// init GEMM (e-order 0..255 sequential fmaf => bit-identical), writes to global.
__global__ __launch_bounds__(1024) void k_keysP2(
    const float* __restrict__ lcv, const float* __restrict__ Wk,
    const float* __restrict__ T1, const float* __restrict__ bk,
    float* __restrict__ keysg, float* __restrict__ P2g)
{
  const int b = blockIdx.x, tid = threadIdx.x, wid = tid >> 6, lane = tid & 63;
  __shared__ __align__(16) float sbuf[20992];   // sA[128][36] + sW[32][256] + sT[32][256]
  float* sA = sbuf;
  float* sW = sbuf + 4608;
  float* sT = sbuf + 12800;
  float4 kacc[8], p2acc[8];
  #pragma unroll
  for (int r = 0; r < 8; ++r){
    kacc[r]  = make_float4(0.f,0.f,0.f,0.f);
    p2acc[r] = make_float4(0.f,0.f,0.f,0.f);
  }
  for (int ch = 0; ch < 8; ++ch){
    const int e0 = ch << 5;
    __syncthreads();
    {
      const int r = tid >> 3, c = tid & 7;
      const float4 t = ((const float4*)(lcv + ((size_t)b*NN + r)*EE + e0))[c];
      ((float4*)sA)[r*9 + c] = t;
    }
    #pragma unroll
    for (int s = 0; s < 2; ++s){
      const int idx4 = s*1024 + tid;
      const int e = idx4 >> 6, c = idx4 & 63;
      ((float4*)sW)[idx4] = ((const float4*)(Wk + (size_t)(e0+e)*HH))[c];
      ((float4*)sT)[idx4] = ((const float4*)(T1 + (size_t)(EE+e0+e)*HH))[c];
    }
    __syncthreads();
    const float* aRow = sA + (wid << 3)*36;
    for (int e = 0; e < 32; ++e){
      const float4 wv = ((const float4*)sW)[(e<<6) + lane];
      const float4 tv = ((const float4*)sT)[(e<<6) + lane];
      #pragma unroll
      for (int r = 0; r < 8; ++r){
        const float av = aRow[r*36 + e];
        kacc[r].x = fmaf(av, wv.x, kacc[r].x);
        kacc[r].y = fmaf(av, wv.y, kacc[r].y);
        kacc[r].z = fmaf(av, wv.z, kacc[r].z);
        kacc[r].w = fmaf(av, wv.w, kacc[r].w);
        p2acc[r].x = fmaf(av, tv.x, p2acc[r].x);
        p2acc[r].y = fmaf(av, tv.y, p2acc[r].y);
        p2acc[r].z = fmaf(av, tv.z, p2acc[r].z);
        p2acc[r].w = fmaf(av, tv.w, p2acc[r].w);
      }
    }
  }
  const float4 bkv = ((const float4*)bk)[lane];
  #pragma unroll
  for (int r = 0; r < 8; ++r){
    const int j = (wid << 3) + r;
    float4 kv = kacc[r];
    kv.x += bkv.x; kv.y += bkv.y; kv.z += bkv.z; kv.w += bkv.w;
    ((float4*)(keysg + ((size_t)b*NN + j)*EE))[lane] = kv;
    ((float4*)(P2g   + ((size_t)b*NN + j)*EE))[lane] = p2acc[r];
  }
}

// l_tab[b][128][j] (the query0 row): l = 10*tanh(sum_h tanh(keys+q0)*v)
__global__ void k_l0(const float* __restrict__ keysg, const float* __restrict__ base,
                     const float* __restrict__ c0, const float* __restrict__ vvec,
                     float* __restrict__ l_tab){
  const int b = blockIdx.x, j = threadIdx.x;   // 128 threads
  __shared__ float q0[EE];
  __shared__ float vsh[EE];
  q0[j]       = base[(size_t)b*HH + j]       + c0[j];
  q0[j + 128] = base[(size_t)b*HH + j + 128] + c0[j + 128];
  vsh[j] = vvec[j]; vsh[j+128] = vvec[j+128];
  __syncthreads();
  const float* krow = keysg + ((size_t)b*NN + j)*EE;
  float acc = 0.f;
  #pragma unroll 4
  for (int e = 0; e < EE; ++e)
    acc = fmaf(fast_tanhf(krow[e] + q0[e]), vsh[e], acc);
  l_tab[((size_t)b*129 + 128)*NN + j] = 10.0f * fast_tanhf(acc);
}

// step-0 decision (idx0 per batch): same data+algorithm as k_seq's step 0
__global__ void k_idx0(const float* __restrict__ l_tab, const int* __restrict__ mask_in,
                       const int* __restrict__ id_in, int* __restrict__ idx0){
  const int b = blockIdx.x, lane = threadIdx.x;   // 64 threads
  const float NEG_INF = -__builtin_huge_valf();
  float l0 = l_tab[((size_t)b*129 + 128)*NN + lane];
  float l1 = l_tab[((size_t)b*129 + 128)*NN + 64 + lane];
  if (mask_in[(size_t)b*NN + lane])      l0 = NEG_INF;
  if (mask_in[(size_t)b*NN + 64 + lane]) l1 = NEG_INF;
  uint32_t k0, k1; tf2x32(0u, 42u, 0u, 0u, k0, k1);
  const float g0 = jax_gumbel(k0, k1, (uint32_t)(b*NN + lane));
  const float g1 = jax_gumbel(k0, k1, (uint32_t)(b*NN + 64 + lane));
  float y = l0 + g0; int pj = lane;
  { float yb = l1 + g1; if (yb > y){ y = yb; pj = 64 + lane; } }
  float es = 0.f;   // unused here
  CMB_DPP(0xB1); CMB_DPP(0x4E); CMB_DPP(0x124); CMB_DPP(0x128);
  CMB_SWZ16(); CMB_SHF32();
  int bi = pj;
  if (id_in[0] == 0) bi = 0;
  if (lane == 0) idx0[b] = bi;
}

// qb[b] = base[b] + lcv[b, idx0]@T1a  (same bracketing as round-4's p1row)
__global__ void k_qb(const float* __restrict__ lcv, const float* __restrict__ T1,
                     const float* __restrict__ base, const int* __restrict__ idx0,
                     float* __restrict__ qb){
  const int b = blockIdx.x, h = threadIdx.x;   // 256 threads
  const float* arow = lcv + ((size_t)b*NN + idx0[b])*EE;
  float acc = 0.f;
  #pragma unroll 4
  for (int e = 0; e < EE; ++e) acc = fmaf(arow[e], T1[(size_t)e*HH + h], acc);
  qb[(size_t)b*HH + h] = base[(size_t)b*HH + h] + acc;
}

// The big table: l_tab[b][idx][j] = 10*tanh(sum_h tanh(keys[j,h] + qb[h] + P2[idx,h]) * v[h])
// block = (b, jt): 32 j's x 128 idx x 256 h. 256 threads: thread=(jq=t&7, iq=t>>3).
__global__ __launch_bounds__(256) void k_tab(
    const float* __restrict__ keysg, const float* __restrict__ P2g,
    const float* __restrict__ qb, const float* __restrict__ vvec,
    float* __restrict__ l_tab)
{
  const int b  = blockIdx.x >> 2;
  const int jt = blockIdx.x & 3;
  const int t = threadIdx.x;
  __shared__ __align__(16) float skeys[32*65*4];   // [32 rows][65 f4], xor-swizzled
  __shared__ __align__(16) float sQ2[32*65*4];     // [32 rows][65 f4]
  __shared__ __align__(16) float sv[EE];
  __shared__ __align__(16) float sqb[EE];

  #pragma unroll
  for (int k = 0; k < 8; ++k){
    const int idx4 = t + 256*k;                // 0..2047
    const int row = idx4 >> 6, hc = idx4 & 63;
    const float4 kv = ((const float4*)(keysg + ((size_t)b*NN + jt*32 + row)*EE))[hc];
    ((float4*)skeys)[row*65 + (hc ^ ((row >> 2) & 7))] = kv;
  }
  if (t < 64){
    ((float4*)sv)[t]  = ((const float4*)vvec)[t];
    ((float4*)sqb)[t] = ((const float4*)(qb + (size_t)b*HH))[t];
  }
  const int jq = t & 7;       // j-quad: j = jq*4 + jj
  const int iq = t >> 3;      // idx within 32-chunk

  for (int ib = 0; ib < 4; ++ib){
    __syncthreads();
    #pragma unroll
    for (int k = 0; k < 8; ++k){
      const int idx4 = t + 256*k;
      const int row = idx4 >> 6, hc = idx4 & 63;
      float4 pv = ((const float4*)(P2g + ((size_t)b*NN + ib*32 + row)*EE))[hc];
      const float4 qv = ((const float4*)sqb)[hc];
      pv.x += qv.x; pv.y += qv.y; pv.z += qv.z; pv.w += qv.w;
      ((float4*)sQ2)[row*65 + hc] = pv;
    }
    __syncthreads();
    float a0 = 0.f, a1 = 0.f, a2 = 0.f, a3 = 0.f;
    #pragma unroll 2
    for (int hc = 0; hc < 64; ++hc){
      const float4 qv = ((const float4*)sQ2)[iq*65 + hc];
      const float4 vv = ((const float4*)sv)[hc];
      const int hx = hc ^ jq;                  // matches write swizzle ((row>>2)&7)=jq
      const float4 k0 = ((const float4*)skeys)[(jq*4 + 0)*65 + hx];
      const float4 k1 = ((const float4*)skeys)[(jq*4 + 1)*65 + hx];
      const float4 k2 = ((const float4*)skeys)[(jq*4 + 2)*65 + hx];
      const float4 k3 = ((const float4*)skeys)[(jq*4 + 3)*65 + hx];
      a0 = fmaf(fast_tanhf(k0.x + qv.x), vv.x, a0);
      a0 = fmaf(fast_tanhf(k0.y + qv.y), vv.y, a0);
      a0 = fmaf(fast_tanhf(k0.z + qv.z), vv.z, a0);
      a0 = fmaf(fast_tanhf(k0.w + qv.w), vv.w, a0);
      a1 = fmaf(fast_tanhf(k1.x + qv.x), vv.x, a1);
      a1 = fmaf(fast_tanhf(k1.y + qv.y), vv.y, a1);
      a1 = fmaf(fast_tanhf(k1.z + qv.z), vv.z, a1);
      a1 = fmaf(fast_tanhf(k1.w + qv.w), vv.w, a1);
      a2 = fmaf(fast_tanhf(k2.x + qv.x), vv.x, a2);
      a2 = fmaf(fast_tanhf(k2.y + qv.y), vv.y, a2);
      a2 = fmaf(fast_tanhf(k2.z + qv.z), vv.z, a2);
      a2 = fmaf(fast_tanhf(k2.w + qv.w), vv.w, a2);
      a3 = fmaf(fast_tanhf(k3.x + qv.x), vv.x, a3);
      a3 = fmaf(fast_tanhf(k3.y + qv.y), vv.y, a3);
      a3 = fmaf(fast_tanhf(k3.z + qv.z), vv.z, a3);
      a3 = fmaf(fast_tanhf(k3.w + qv.w), vv.w, a3);
    }
    const int idx = ib*32 + iq;
    float* dst = l_tab + ((size_t)b*129 + idx)*NN + jt*32 + jq*4;
    dst[0] = 10.0f * fast_tanhf(a0);
    dst[1] = 10.0f * fast_tanhf(a1);
    dst[2] = 10.0f * fast_tanhf(a2);
    dst[3] = 10.0f * fast_tanhf(a3);
  }
}

// Sequential sampler: 1 block/batch, table+gumbels staged in LDS, then a
// single wave runs 128 steps with ZERO barriers.
__global__ __launch_bounds__(256) void k_seq(
    const float* __restrict__ l_tab, const float* __restrict__ onode,
    const int* __restrict__ mask_in, const int* __restrict__ id_in,
    float* __restrict__ out)
{
  const int b = blockIdx.x;
  const int tid = threadIdx.x;
  const int wid = tid >> 6;
  const int lane = tid & 63;
  __shared__ float l_s[129*NN];      // 66048 B
  __shared__ float g_a[NN*NN];       // 65536 B
  __shared__ float2 on_s[NN];
  __shared__ int   mask_s[NN];
  __shared__ uint32_t sk0[NN], sk1[NN];

  // stage phase 1: l-table slab, step keys, mask, nodes
  #pragma unroll
  for (int k = 0; k < 17; ++k){
    const int i4 = tid + 256*k;
    if (i4 < (129*NN)/4)
      ((float4*)l_s)[i4] = ((const float4*)(l_tab + (size_t)b*129*NN))[i4];
  }
  if (tid < NN){
    uint32_t o0, o1; tf2x32(0u, 42u, 0u, (uint32_t)tid, o0, o1);
    sk0[tid] = o0; sk1[tid] = o1;
    mask_s[tid] = mask_in[(size_t)b*NN + tid];
    on_s[tid] = ((const float2*)onode)[b*NN + tid];
  }
  __syncthreads();
  // stage phase 2: all 16384 gumbels (all 4 waves help)
  for (int k = 0; k < 64; ++k){
    const int p = tid + 256*k;
    const int i = p >> 7, j = p & 127;
    g_a[p] = jax_gumbel(sk0[i], sk1[i], (uint32_t)(b*NN + j));
  }
  __syncthreads();
  if (wid != 0) return;   // waves 1-3 done

  const int id0 = id_in[0];
  const float NEG_INF = -__builtin_huge_valf();
  if (lane == 0){
    out[OFF_INIT + 2*b]     = on_s[0].x;
    out[OFF_INIT + 2*b + 1] = on_s[0].y;
  }
  int prev = 128, cur = 0;
  for (int i = 0; i < NN; ++i){
    float l0 = l_s[prev*NN + lane];
    float l1 = l_s[prev*NN + 64 + lane];
    if (mask_s[lane])      l0 = NEG_INF;
    if (mask_s[64 + lane]) l1 = NEG_INF;
    float y = l0 + g_a[i*NN + lane]; int pj = lane;
    { float yb = l1 + g_a[i*NN + 64 + lane];
      if (yb > y){ y = yb; pj = 64 + lane; } }
    float es = __expf(l0) + __expf(l1);
    CMB_DPP(0xB1); CMB_DPP(0x4E); CMB_DPP(0x124); CMB_DPP(0x128);
    CMB_SWZ16(); CMB_SHF32();
    int bi = pj;
    if (i == 0 && id0 == 0) bi = 0;
    const float lsel = __shfl((bi & 64) ? l1 : l0, bi & 63);
    const float logp = lsel - __logf(es);
    if (lane == 0){
      out[OFF_LOGP + b*NN + i] = logp;
      out[OFF_IDX  + b*NN + i] = (float)bi;
      const float2 pc = on_s[cur];
      const float2 pn = on_s[bi];
      const float dx = pn.x - pc.x, dy = pn.y - pc.y;
      out[OFF_RS + b*NN + i] = sqrtf(dx*dx + dy*dy);
      if (i == NN-1){ out[OFF_LAST + 2*b] = pn.x; out[OFF_LAST + 2*b + 1] = pn.y; }
      mask_s[bi] = 1;
      cur = bi;
    }
    prev = bi;
  }
}

// ================= FALLBACK: round-4 dec_main (known-pass, 805us) =================
__global__ __launch_bounds__(1024, 4) void dec_main(
    const float* __restrict__ lcv, const float* __restrict__ onode,
    const int* __restrict__ mask_in, const int* __restrict__ id_in,
    const float* __restrict__ Wk, const float* __restrict__ bk,
    const float* __restrict__ vvec, const float* __restrict__ T1,
    const float* __restrict__ base, const float* __restrict__ tmp1,
    const float* __restrict__ Wq, float* __restrict__ out)
{
  const int b = blockIdx.x;
  const int tid = threadIdx.x;
  const int wid = tid >> 6;
  const int lane = tid & 63;

  __shared__ __align__(16) float keys_lds[NN*KST];
  __shared__ __align__(16) float q_s[272];
  __shared__ __align__(16) float base_s[HH];
  __shared__ __align__(16) float p1row[HH];
  __shared__ __align__(16) float2 on_s[NN];
  __shared__ float u_s[NN];
  __shared__ float g2_s[2][NN];
  __shared__ int act_s[NN];
  __shared__ int pos_s[NN];
  __shared__ int mask_s[NN];
  __shared__ uint32_t sk0[NN], sk1[NN];
  __shared__ int idx_sh, L_sh;

  const float NEG_INF = -__builtin_huge_valf();
  const int id0 = id_in[0];

  float4 kacc[8], p2acc[8];
  #pragma unroll
  for (int r = 0; r < 8; ++r){
    kacc[r]  = make_float4(0.f,0.f,0.f,0.f);
    p2acc[r] = make_float4(0.f,0.f,0.f,0.f);
  }
  {
    float* sA = keys_lds;
    float* sW = keys_lds + 4608;
    float* sT = keys_lds + 12800;
    for (int ch = 0; ch < 8; ++ch){
      const int e0 = ch << 5;
      __syncthreads();
      {
        const int r = tid >> 3, c = tid & 7;
        const float4 t = ((const float4*)(lcv + ((size_t)b*NN + r)*EE + e0))[c];
        ((float4*)sA)[r*9 + c] = t;
      }
      #pragma unroll
      for (int s = 0; s < 2; ++s){
        const int idx4 = s*1024 + tid;
        const int e = idx4 >> 6, c = idx4 & 63;
        ((float4*)sW)[idx4] = ((const float4*)(Wk + (size_t)(e0+e)*HH))[c];
        ((float4*)sT)[idx4] = ((const float4*)(T1 + (size_t)(EE+e0+e)*HH))[c];
      }
      __syncthreads();
      const float* aRow = sA + (wid << 3)*36;
      for (int e = 0; e < 32; ++e){
        const float4 wv = ((const float4*)sW)[(e<<6) + lane];
        const float4 tv = ((const float4*)sT)[(e<<6) + lane];
        #pragma unroll
        for (int r = 0; r < 8; ++r){
          const float av = aRow[r*36 + e];
          kacc[r].x = fmaf(av, wv.x, kacc[r].x);
          kacc[r].y = fmaf(av, wv.y, kacc[r].y);
          kacc[r].z = fmaf(av, wv.z, kacc[r].z);
          kacc[r].w = fmaf(av, wv.w, kacc[r].w);
          p2acc[r].x = fmaf(av, tv.x, p2acc[r].x);
          p2acc[r].y = fmaf(av, tv.y, p2acc[r].y);
          p2acc[r].z = fmaf(av, tv.z, p2acc[r].z);
          p2acc[r].w = fmaf(av, tv.w, p2acc[r].w);
        }
      }
    }
  }
  __syncthreads();
  {
    const float4 bkv = ((const float4*)bk)[lane];
    const int sphys = ((lane >> 4) << 4) | ((lane & 15) ^ (lane >> 4));
    #pragma unroll
    for (int r = 0; r < 8; ++r){
      const int j = (wid << 3) + r;
      float4 kv = kacc[r];
      kv.x += bkv.x; kv.y += bkv.y; kv.z += bkv.z; kv.w += bkv.w;
      ((float4*)keys_lds)[j*KST4 + sphys] = kv;
    }
  }

  const int grp = tid & 3;
  const int aslot = tid >> 2;

  float4 vreg[16];
  #pragma unroll
  for (int c = 0; c < 16; ++c) vreg[c] = ((const float4*)vvec)[(grp << 4) + c];

  if (tid < HH){
    const float bs = base[(size_t)b*HH + tid];
    base_s[tid] = bs;
    float c0v = 0.f;
    for (int e = 0; e < EE; ++e) c0v = fmaf(tmp1[e], Wq[(size_t)e*HH + tid], c0v);
    q_s[(tid>>6)*68 + (tid&63)] = bs + c0v;
  } else if (tid < HH + NN){
    const int j = tid - HH;
    mask_s[j] = mask_in[(size_t)b*NN + j];
    uint32_t o0,o1; tf2x32(0u, 42u, 0u, (uint32_t)j, o0, o1);
    sk0[j] = o0; sk1[j] = o1;
  } else if (tid == HH + NN){
    out[OFF_INIT + 2*b]     = onode[(size_t)b*NN*2 + 0];
    out[OFF_INIT + 2*b + 1] = onode[(size_t)b*NN*2 + 1];
  } else if (tid >= 512 && tid < 512 + NN){
    on_s[tid - 512] = ((const float2*)onode)[b*NN + (tid - 512)];
  }
  __syncthreads();
  if (tid == 0){
    int L = 0;
    for (int j = 0; j < NN; ++j){
      if (mask_s[j] == 0){ act_s[L] = j; pos_s[j] = L; ++L; }
    }
    L_sh = L;
  }
  if (wid == 15){
    g2_s[0][lane]      = jax_gumbel(sk0[0], sk1[0], (uint32_t)(b*NN + lane));
    g2_s[0][64 + lane] = jax_gumbel(sk0[0], sk1[0], (uint32_t)(b*NN + 64 + lane));
  }

  int cur = 0;

  for (int i = 0; i < NN; ++i){
    __syncthreads();
    const int L = L_sh;
    if (aslot < L){
      const int j = act_s[aslot];
      const int kb4 = j*KST4 + (grp << 4);
      const int qb4 = grp*17;
      float s = 0.f;
      #pragma unroll
      for (int c4 = 0; c4 < 4; ++c4){
        float th[16];
        #pragma unroll
        for (int cc = 0; cc < 4; ++cc){
          const int c = c4*4 + cc;
          const float4 kv = ((const float4*)keys_lds)[kb4 + (c ^ grp)];
          const float4 qv = ((const float4*)q_s)[qb4 + c];
          th[4*cc+0] = fast_tanhf(kv.x + qv.x);
          th[4*cc+1] = fast_tanhf(kv.y + qv.y);
          th[4*cc+2] = fast_tanhf(kv.z + qv.z);
          th[4*cc+3] = fast_tanhf(kv.w + qv.w);
        }
        #pragma unroll
        for (int cc = 0; cc < 4; ++cc){
          const float4 vv = vreg[c4*4 + cc];
          s = fmaf(th[4*cc+0], vv.x, s);
          s = fmaf(th[4*cc+1], vv.y, s);
          s = fmaf(th[4*cc+2], vv.z, s);
          s = fmaf(th[4*cc+3], vv.w, s);
        }
      }
      s += __shfl_xor(s, 1);
      s += __shfl_xor(s, 2);
      if (grp == 0) u_s[j] = s;
    } else if (wid == 15 && i + 1 < NN){
      const int nb = (i + 1) & 1;
      g2_s[nb][lane]      = jax_gumbel(sk0[i+1], sk1[i+1], (uint32_t)(b*NN + lane));
      g2_s[nb][64 + lane] = jax_gumbel(sk0[i+1], sk1[i+1], (uint32_t)(b*NN + 64 + lane));
    }
    __syncthreads();
    float l0 = 0.f, l1 = 0.f; int bi = 0;
    if (wid == 0){
      l0 = 10.0f * fast_tanhf(u_s[lane]);
      l1 = 10.0f * fast_tanhf(u_s[64 + lane]);
      if (mask_s[lane])      l0 = NEG_INF;
      if (mask_s[64 + lane]) l1 = NEG_INF;
      const float y0 = l0 + g2_s[i & 1][lane];
      const float y1 = l1 + g2_s[i & 1][64 + lane];
      float bv;
      if (y1 > y0){ bv = y1; bi = 64 + lane; } else { bv = y0; bi = lane; }
      #pragma unroll
      for (int off = 1; off < 64; off <<= 1){
        const float ov = __shfl_xor(bv, off);
        const int   oi = __shfl_xor(bi, off);
        if (ov > bv || (ov == bv && oi < bi)){ bv = ov; bi = oi; }
      }
      if (i == 0 && id0 == 0) bi = 0;
      if (lane == 0) idx_sh = bi;
    }
    __syncthreads();
    const int idx = idx_sh;
    if (i == 0){
      if (tid < HH){
        const float* arow = lcv + ((size_t)b*NN + idx)*EE;
        float acc = 0.f;
        for (int e = 0; e < EE; ++e) acc = fmaf(arow[e], T1[(size_t)e*HH + tid], acc);
        p1row[tid] = acc;
      }
      __syncthreads();
    }
    if (wid == (idx >> 3)){
      const int r2 = idx & 7;
      float4 pp;
      switch (r2){
        case 0: pp = p2acc[0]; break;
        case 1: pp = p2acc[1]; break;
        case 2: pp = p2acc[2]; break;
        case 3: pp = p2acc[3]; break;
        case 4: pp = p2acc[4]; break;
        case 5: pp = p2acc[5]; break;
        case 6: pp = p2acc[6]; break;
        default: pp = p2acc[7]; break;
      }
      const float4 b4 = ((const float4*)base_s)[lane];
      const float4 p4 = ((const float4*)p1row)[lane];
      float4 nq;
      nq.x = (b4.x + p4.x) + pp.x;
      nq.y = (b4.y + p4.y) + pp.y;
      nq.z = (b4.z + p4.z) + pp.z;
      nq.w = (b4.w + p4.w) + pp.w;
      ((float4*)q_s)[((lane >> 4)*17) + (lane & 15)] = nq;
    }
    if (wid == 0){
      float es = __expf(l0) + __expf(l1);
      #pragma unroll
      for (int off = 1; off < 64; off <<= 1) es += __shfl_xor(es, off);
      const float lown = (bi >= 64) ? l1 : l0;
      const float lsel = __shfl(lown, bi & 63);
      const float logp = lsel - __logf(es);
      if (lane == 0){
        out[OFF_LOGP + b*NN + i] = logp;
        out[OFF_IDX  + b*NN + i] = (float)bi;
        const float2 pc = on_s[cur];
        const float2 pn = on_s[bi];
        const float dx = pn.x - pc.x, dy = pn.y - pc.y;
        out[OFF_RS + b*NN + i] = sqrtf(dx*dx + dy*dy);
        if (i == NN-1){ out[OFF_LAST + 2*b] = pn.x; out[OFF_LAST + 2*b + 1] = pn.y; }
        cur = bi;
        if (mask_s[bi] == 0){
          mask_s[bi] = 1;
          const int p = pos_s[bi];
          const int Lm = L_sh - 1;
          const int last = act_s[Lm];
          act_s[p] = last;
          pos_s[last] = p;
          L_sh = Lm;
        }
      }
    }
  }
}

extern "C" void kernel_launch(void* const* d_in, const int* in_sizes, int n_in,
                              void* d_out, int out_size, void* d_ws, size_t ws_size,
                              hipStream_t stream){
  const float* lcv   = (const float*)d_in[0];
  const float* onode = (const float*)d_in[1];
  const int*   mask  = (const int*)d_in[2];
  const int*   id    = (const int*)d_in[3];
  const float* liw   = (const float*)d_in[4];
  const float* Whbar = (const float*)d_in[5];
  const float* bhbar = (const float*)d_in[6];
  const float* Wrest = (const float*)d_in[7];
  const float* brest = (const float*)d_in[8];
  const float* Wk    = (const float*)d_in[9];
  const float* bk    = (const float*)d_in[10];
  const float* Wq    = (const float*)d_in[11];
  const float* bq    = (const float*)d_in[12];
  const float* vv    = (const float*)d_in[13];

  float* ws  = (float*)d_ws;
  float* out = (float*)d_out;

  const size_t NEED_BYTES = 21267200ull * 4ull;   // 81.1 MB

  if (ws_size >= NEED_BYTES){
    float* T1   = ws;                 // 131072
    float* base = ws + 131072;        // 65536
    float* tmp1 = ws + 196608;        // 256
    float* c0   = ws + 196864;        // 256
    float* qb   = ws + 197120;        // 65536
    int*   idx0 = (int*)(ws + 262656);// 256
    float* keys = ws + 262912;        // 8388608
    float* P2   = ws + 8651520;       // 8388608
    float* ltab = ws + 17040128;      // 4227072

    hipLaunchKernelGGL(k_tmp1,   dim3(1),    dim3(256),  0, stream, liw, Wrest, tmp1);
    hipLaunchKernelGGL(k_c0,     dim3(1),    dim3(256),  0, stream, tmp1, Wq, c0);
    hipLaunchKernelGGL(k_T1,     dim3(512),  dim3(256),  0, stream, Wrest, Wq, T1);
    hipLaunchKernelGGL(k_base,   dim3(256),  dim3(256),  0, stream, lcv, Whbar, bhbar, brest, Wq, bq, base);
    hipLaunchKernelGGL(k_keysP2, dim3(256),  dim3(1024), 0, stream, lcv, Wk, T1, bk, keys, P2);
    hipLaunchKernelGGL(k_l0,     dim3(256),  dim3(128),  0, stream, keys, base, c0, vv, ltab);
    hipLaunchKernelGGL(k_idx0,   dim3(256),  dim3(64),   0, stream, ltab, mask, id, idx0);
    hipLaunchKernelGGL(k_qb,     dim3(256),  dim3(256),  0, stream, lcv, T1, base, idx0, qb);
    hipLaunchKernelGGL(k_tab,    dim3(1024), dim3(256),  0, stream, keys, P2, qb, vv, ltab);
    hipLaunchKernelGGL(k_seq,    dim3(256),  dim3(256),  0, stream, ltab, onode, mask, id, out);
  } else {
    // fallback: round-4 path (known-pass)
    float* T1   = ws;            // 512*256
    float* base = ws + 131072;   // 256*256
    float* tmp1 = ws + 196608;   // 256

    hipLaunchKernelGGL(k_tmp1, dim3(1),   dim3(256), 0, stream, liw, Wrest, tmp1);
    hipLaunchKernelGGL(k_T1,   dim3(512), dim3(256), 0, stream, Wrest, Wq, T1);
    hipLaunchKernelGGL(k_base, dim3(256), dim3(256), 0, stream, lcv, Whbar, bhbar, brest, Wq, bq, base);
    hipLaunchKernelGGL(dec_main, dim3(256), dim3(1024), 0, stream,
                       lcv, onode, mask, id, Wk, bk, vv, T1, base, tmp1, Wq, out);
  }
}

// Round 6
// 529.306 us; speedup vs baseline: 1.5213x; 1.1714x over previous
//
#include <hip/hip_runtime.h>
#include <stdint.h>
#include <math.h>

#define NN 128
#define EE 256
#define HH 256

#define OFF_LOGP 0
#define OFF_IDX  32768
#define OFF_INIT 65536
#define OFF_LAST 66048
#define OFF_RS   66560

// keys row stride in floats / float4 slots (padded: 260 = 65*4) -- fallback path
#define KST  260
#define KST4 65

__device__ __forceinline__ uint32_t rotl32_(uint32_t x, int d){ return (x<<d)|(x>>(32-d)); }

// Threefry-2x32, 20 rounds, JAX key schedule (bit-identical to rounds 1-5)
__device__ __forceinline__ void tf2x32(uint32_t k0, uint32_t k1, uint32_t x0, uint32_t x1,
                                       uint32_t& o0, uint32_t& o1){
  uint32_t k2 = k0 ^ k1 ^ 0x1BD11BDAu;
  x0 += k0; x1 += k1;
#define TF_RND(r) { x0 += x1; x1 = rotl32_(x1,(r)); x1 ^= x0; }
  TF_RND(13) TF_RND(15) TF_RND(26) TF_RND(6)
  x0 += k1; x1 += k2 + 1u;
  TF_RND(17) TF_RND(29) TF_RND(16) TF_RND(24)
  x0 += k2; x1 += k0 + 2u;
  TF_RND(13) TF_RND(15) TF_RND(26) TF_RND(6)
  x0 += k0; x1 += k1 + 3u;
  TF_RND(17) TF_RND(29) TF_RND(16) TF_RND(24)
  x0 += k1; x1 += k2 + 4u;
  TF_RND(13) TF_RND(15) TF_RND(26) TF_RND(6)
  x0 += k2; x1 += k0 + 5u;
#undef TF_RND
  o0 = x0; o1 = x1;
}

// Refined fast tanh (round-4/5 function, passed twice): ~0.5 ulp division
__device__ __forceinline__ float fast_tanhf(float x){
  float ax = __builtin_fabsf(x);
  float E = __builtin_amdgcn_exp2f(ax * -2.885390081777927f);  // 2^(-2*log2(e)*|x|)
  float num = 1.0f - E;
  float den = 1.0f + E;
  float inv = __builtin_amdgcn_rcpf(den);
  inv = fmaf(fmaf(-den, inv, 1.0f), inv, inv);   // Newton refine
  float r = num * inv;
  r = fmaf(fmaf(-den, r, num), inv, r);          // residual correction
  return __builtin_copysignf(r, x);
}

// Raw-rcp tanh for the k_tab inner loop ONLY (~2 ulp, abs err ~2.4e-7; weighted
// by |v|<=1/16 over 256 terms -> logit perturbation ~1e-6). 10 fewer cycles/elem.
__device__ __forceinline__ float tanh_raw(float x){
  float ax = __builtin_fabsf(x);
  float E = __builtin_amdgcn_exp2f(ax * -2.885390081777927f);
  float r = (1.0f - E) * __builtin_amdgcn_rcpf(1.0f + E);
  return __builtin_copysignf(r, x);
}

// jax.random.gumbel element — bit-identical to rounds 1-5 (feeds argmax: IEEE logf)
__device__ __forceinline__ float jax_gumbel(uint32_t k0, uint32_t k1, uint32_t t){
  uint32_t o0, o1, bits;
  tf2x32(k0, k1, 0u, t, o0, o1);
  bits = o0 ^ o1;
  float u = __uint_as_float((bits >> 9) | 0x3f800000u) - 1.0f;
  const float kTiny = 1.17549435e-38f;
  u = fmaxf(kTiny, u + kTiny);
  return -logf(-logf(u));
}

// Wave-wide argmax(+sum) reduce: quad_perm xor1/xor2 + row_ror4/8 (DPP) +
// ds_swizzle xor16 + shfl xor32. Associative w/ smallest-index tie-break.
#define CMB_DPP(CTRL) { \
  float ny_ = __int_as_float(__builtin_amdgcn_mov_dpp(__float_as_int(y), (CTRL), 0xf, 0xf, false)); \
  int   nj_ = __builtin_amdgcn_mov_dpp(pj, (CTRL), 0xf, 0xf, false); \
  float ne_ = __int_as_float(__builtin_amdgcn_mov_dpp(__float_as_int(es), (CTRL), 0xf, 0xf, false)); \
  es += ne_; \
  if (ny_ > y || (ny_ == y && nj_ < pj)){ y = ny_; pj = nj_; } }
#define CMB_SWZ16() { \
  float ny_ = __int_as_float(__builtin_amdgcn_ds_swizzle(__float_as_int(y), 0x401F)); \
  int   nj_ = __builtin_amdgcn_ds_swizzle(pj, 0x401F); \
  float ne_ = __int_as_float(__builtin_amdgcn_ds_swizzle(__float_as_int(es), 0x401F)); \
  es += ne_; \
  if (ny_ > y || (ny_ == y && nj_ < pj)){ y = ny_; pj = nj_; } }
#define CMB_SHF32() { \
  float ny_ = __shfl_xor(y, 32); \
  int   nj_ = __shfl_xor(pj, 32); \
  float ne_ = __shfl_xor(es, 32); \
  es += ne_; \
  if (ny_ > y || (ny_ == y && nj_ < pj)){ y = ny_; pj = nj_; } }

// ============ K1: fused precompute (block 0: tmp1+c0 | 1..512: T1 | 513..768: base) ============
__global__ __launch_bounds__(256) void k_pre(
    const float* __restrict__ liw, const float* __restrict__ Wr,
    const float* __restrict__ Wq, const float* __restrict__ lcv,
    const float* __restrict__ Whbar, const float* __restrict__ bhbar,
    const float* __restrict__ brest, const float* __restrict__ bq,
    float* __restrict__ c0, float* __restrict__ T1, float* __restrict__ base)
{
  __shared__ float sbuf[512];
  const int bid = blockIdx.x;
  const int t = threadIdx.x;
  if (bid == 0){
    // tmp1[e] = liw @ W_rest (col e), then c0[h] = tmp1 @ Wq
    float acc = 0.f;
    for (int k = 0; k < 2*EE; ++k) acc = fmaf(liw[k], Wr[(size_t)k*EE + t], acc);
    sbuf[t] = acc;
    __syncthreads();
    float c = 0.f;
    for (int e = 0; e < EE; ++e) c = fmaf(sbuf[e], Wq[(size_t)e*HH + t], c);
    c0[t] = c;
  } else if (bid <= 512){
    const int r = bid - 1;
    float acc = 0.f;
    for (int e = 0; e < EE; ++e) acc = fmaf(Wr[(size_t)r*EE + e], Wq[(size_t)e*HH + t], acc);
    T1[(size_t)r*HH + t] = acc;
  } else {
    const int b = bid - 513;
    float* sm  = sbuf;
    float* hb2 = sbuf + 256;
    float acc = 0.f;
    const float* p = lcv + (size_t)b*NN*EE + t;
    for (int n = 0; n < NN; ++n) acc += p[(size_t)n*EE];
    sm[t] = acc * 0.0078125f;
    __syncthreads();
    float a2 = 0.f;
    for (int e = 0; e < EE; ++e) a2 = fmaf(sm[e], Whbar[(size_t)e*EE + t], a2);
    hb2[t] = (a2 + bhbar[t]) + brest[t];
    __syncthreads();
    float a3 = 0.f;
    for (int e = 0; e < EE; ++e) a3 = fmaf(hb2[e], Wq[(size_t)e*HH + t], a3);
    base[(size_t)b*HH + t] = a3 + bq[t];
  }
}

// ============ K2: keys/P2 GEMM + fused l0 row ============
// keys[b] = lcv[b]@Wk + bk ; P2[b] = lcv[b]@T1b (e-order 0..255 sequential fmaf,
// bit-identical to rounds 2-5); then u0[j] = sum_h tanh(keys+q0)*v via 4-elem
// partial + 64-lane shfl tree, l_tab row 128 = 10*tanh(u0).
__global__ __launch_bounds__(1024) void k_keysP2(
    const float* __restrict__ lcv, const float* __restrict__ Wk,
    const float* __restrict__ T1, const float* __restrict__ bk,
    const float* __restrict__ base, const float* __restrict__ c0,
    const float* __restrict__ vvec,
    float* __restrict__ keysg, float* __restrict__ P2g, float* __restrict__ ltab)
{
  const int b = blockIdx.x, tid = threadIdx.x, wid = tid >> 6, lane = tid & 63;
  __shared__ __align__(16) float sbuf[20992];   // sA[128][36] + sW[32][256] + sT[32][256]
  __shared__ __align__(16) float q0s[EE];
  __shared__ __align__(16) float vs[EE];
  float* sA = sbuf;
  float* sW = sbuf + 4608;
  float* sT = sbuf + 12800;
  if (tid < 64){
    float4 bs = ((const float4*)(base + (size_t)b*HH))[tid];
    const float4 cc = ((const float4*)c0)[tid];
    bs.x += cc.x; bs.y += cc.y; bs.z += cc.z; bs.w += cc.w;
    ((float4*)q0s)[tid] = bs;
    ((float4*)vs)[tid]  = ((const float4*)vvec)[tid];
  }
  float4 kacc[8], p2acc[8];
  #pragma unroll
  for (int r = 0; r < 8; ++r){
    kacc[r]  = make_float4(0.f,0.f,0.f,0.f);
    p2acc[r] = make_float4(0.f,0.f,0.f,0.f);
  }
  for (int ch = 0; ch < 8; ++ch){
    const int e0 = ch << 5;
    __syncthreads();
    {
      const int r = tid >> 3, c = tid & 7;
      const float4 t = ((const float4*)(lcv + ((size_t)b*NN + r)*EE + e0))[c];
      ((float4*)sA)[r*9 + c] = t;
    }
    #pragma unroll
    for (int s = 0; s < 2; ++s){
      const int idx4 = s*1024 + tid;
      const int e = idx4 >> 6, c = idx4 & 63;
      ((float4*)sW)[idx4] = ((const float4*)(Wk + (size_t)(e0+e)*HH))[c];
      ((float4*)sT)[idx4] = ((const float4*)(T1 + (size_t)(EE+e0+e)*HH))[c];
    }
    __syncthreads();
    const float* aRow = sA + (wid << 3)*36;
    for (int e = 0; e < 32; ++e){
      const float4 wv = ((const float4*)sW)[(e<<6) + lane];
      const float4 tv = ((const float4*)sT)[(e<<6) + lane];
      #pragma unroll
      for (int r = 0; r < 8; ++r){
        const float av = aRow[r*36 + e];
        kacc[r].x = fmaf(av, wv.x, kacc[r].x);
        kacc[r].y = fmaf(av, wv.y, kacc[r].y);
        kacc[r].z = fmaf(av, wv.z, kacc[r].z);
        kacc[r].w = fmaf(av, wv.w, kacc[r].w);
        p2acc[r].x = fmaf(av, tv.x, p2acc[r].x);
        p2acc[r].y = fmaf(av, tv.y, p2acc[r].y);
        p2acc[r].z = fmaf(av, tv.z, p2acc[r].z);
        p2acc[r].w = fmaf(av, tv.w, p2acc[r].w);
      }
    }
  }
  const float4 bkv = ((const float4*)bk)[lane];
  const float4 qv0 = ((const float4*)q0s)[lane];
  const float4 vv0 = ((const float4*)vs)[lane];
  #pragma unroll
  for (int r = 0; r < 8; ++r){
    const int j = (wid << 3) + r;
    float4 kv = kacc[r];
    kv.x += bkv.x; kv.y += bkv.y; kv.z += bkv.z; kv.w += bkv.w;
    ((float4*)(keysg + ((size_t)b*NN + j)*EE))[lane] = kv;
    ((float4*)(P2g   + ((size_t)b*NN + j)*EE))[lane] = p2acc[r];
    // fused l0 row
    float p = 0.f;
    p = fmaf(fast_tanhf(kv.x + qv0.x), vv0.x, p);
    p = fmaf(fast_tanhf(kv.y + qv0.y), vv0.y, p);
    p = fmaf(fast_tanhf(kv.z + qv0.z), vv0.z, p);
    p = fmaf(fast_tanhf(kv.w + qv0.w), vv0.w, p);
    #pragma unroll
    for (int off = 1; off < 64; off <<= 1) p += __shfl_xor(p, off);
    if (lane == 0) ltab[((size_t)b*129 + 128)*NN + j] = 10.0f * fast_tanhf(p);
  }
}

// ============ K3: fused idx0 (argmax over l0 row) + qb GEMV ============
__global__ __launch_bounds__(256) void k_idx0qb(
    const float* __restrict__ ltab, const int* __restrict__ mask_in,
    const int* __restrict__ id_in, const float* __restrict__ lcv,
    const float* __restrict__ T1, const float* __restrict__ base,
    float* __restrict__ qb)
{
  const int b = blockIdx.x, t = threadIdx.x, lane = t & 63;
  __shared__ int idx_sh;
  if (t < 64){
    const float NEG_INF = -__builtin_huge_valf();
    float l0 = ltab[((size_t)b*129 + 128)*NN + lane];
    float l1 = ltab[((size_t)b*129 + 128)*NN + 64 + lane];
    if (mask_in[(size_t)b*NN + lane])      l0 = NEG_INF;
    if (mask_in[(size_t)b*NN + 64 + lane]) l1 = NEG_INF;
    uint32_t k0, k1; tf2x32(0u, 42u, 0u, 0u, k0, k1);
    const float g0 = jax_gumbel(k0, k1, (uint32_t)(b*NN + lane));
    const float g1 = jax_gumbel(k0, k1, (uint32_t)(b*NN + 64 + lane));
    float y = l0 + g0; int pj = lane;
    { float yb = l1 + g1; if (yb > y){ y = yb; pj = 64 + lane; } }
    float es = 0.f;   // unused
    CMB_DPP(0xB1); CMB_DPP(0x4E); CMB_DPP(0x124); CMB_DPP(0x128);
    CMB_SWZ16(); CMB_SHF32();
    int bi = pj;
    if (id_in[0] == 0) bi = 0;
    if (lane == 0) idx_sh = bi;
  }
  __syncthreads();
  const int i0 = idx_sh;
  const float* arow = lcv + ((size_t)b*NN + i0)*EE;
  float acc = 0.f;
  #pragma unroll 4
  for (int e = 0; e < EE; ++e) acc = fmaf(arow[e], T1[(size_t)e*HH + t], acc);
  qb[(size_t)b*HH + t] = base[(size_t)b*HH + t] + acc;
}

// ============ K4: the big table ============
// l_tab[b][idx][j] = 10*tanh(sum_h tanh_raw(keys[j,h] + qb[h] + P2[idx,h]) * v[h])
__global__ __launch_bounds__(256) void k_tab(
    const float* __restrict__ keysg, const float* __restrict__ P2g,
    const float* __restrict__ qb, const float* __restrict__ vvec,
    float* __restrict__ l_tab)
{
  const int b  = blockIdx.x >> 2;
  const int jt = blockIdx.x & 3;
  const int t = threadIdx.x;
  __shared__ __align__(16) float skeys[32*65*4];   // [32 rows][65 f4], xor-swizzled
  __shared__ __align__(16) float sQ2[32*65*4];     // [32 rows][65 f4]
  __shared__ __align__(16) float sv[EE];
  __shared__ __align__(16) float sqb[EE];

  #pragma unroll
  for (int k = 0; k < 8; ++k){
    const int idx4 = t + 256*k;                // 0..2047
    const int row = idx4 >> 6, hc = idx4 & 63;
    const float4 kv = ((const float4*)(keysg + ((size_t)b*NN + jt*32 + row)*EE))[hc];
    ((float4*)skeys)[row*65 + (hc ^ ((row >> 2) & 7))] = kv;
  }
  if (t < 64){
    ((float4*)sv)[t]  = ((const float4*)vvec)[t];
    ((float4*)sqb)[t] = ((const float4*)(qb + (size_t)b*HH))[t];
  }
  const int jq = t & 7;       // j-quad: j = jq*4 + jj
  const int iq = t >> 3;      // idx within 32-chunk

  for (int ib = 0; ib < 4; ++ib){
    __syncthreads();
    #pragma unroll
    for (int k = 0; k < 8; ++k){
      const int idx4 = t + 256*k;
      const int row = idx4 >> 6, hc = idx4 & 63;
      float4 pv = ((const float4*)(P2g + ((size_t)b*NN + ib*32 + row)*EE))[hc];
      const float4 qv = ((const float4*)sqb)[hc];
      pv.x += qv.x; pv.y += qv.y; pv.z += qv.z; pv.w += qv.w;
      ((float4*)sQ2)[row*65 + hc] = pv;
    }
    __syncthreads();
    float a0 = 0.f, a1 = 0.f, a2 = 0.f, a3 = 0.f;
    #pragma unroll 2
    for (int hc = 0; hc < 64; ++hc){
      const float4 qv = ((const float4*)sQ2)[iq*65 + hc];
      const float4 vv = ((const float4*)sv)[hc];
      const int hx = hc ^ jq;                  // matches write swizzle ((row>>2)&7)=jq
      const float4 k0 = ((const float4*)skeys)[(jq*4 + 0)*65 + hx];
      const float4 k1 = ((const float4*)skeys)[(jq*4 + 1)*65 + hx];
      const float4 k2 = ((const float4*)skeys)[(jq*4 + 2)*65 + hx];
      const float4 k3 = ((const float4*)skeys)[(jq*4 + 3)*65 + hx];
      a0 = fmaf(tanh_raw(k0.x + qv.x), vv.x, a0);
      a0 = fmaf(tanh_raw(k0.y + qv.y), vv.y, a0);
      a0 = fmaf(tanh_raw(k0.z + qv.z), vv.z, a0);
      a0 = fmaf(tanh_raw(k0.w + qv.w), vv.w, a0);
      a1 = fmaf(tanh_raw(k1.x + qv.x), vv.x, a1);
      a1 = fmaf(tanh_raw(k1.y + qv.y), vv.y, a1);
      a1 = fmaf(tanh_raw(k1.z + qv.z), vv.z, a1);
      a1 = fmaf(tanh_raw(k1.w + qv.w), vv.w, a1);
      a2 = fmaf(tanh_raw(k2.x + qv.x), vv.x, a2);
      a2 = fmaf(tanh_raw(k2.y + qv.y), vv.y, a2);
      a2 = fmaf(tanh_raw(k2.z + qv.z), vv.z, a2);
      a2 = fmaf(tanh_raw(k2.w + qv.w), vv.w, a2);
      a3 = fmaf(tanh_raw(k3.x + qv.x), vv.x, a3);
      a3 = fmaf(tanh_raw(k3.y + qv.y), vv.y, a3);
      a3 = fmaf(tanh_raw(k3.z + qv.z), vv.z, a3);
      a3 = fmaf(tanh_raw(k3.w + qv.w), vv.w, a3);
    }
    const int idx = ib*32 + iq;
    float* dst = l_tab + ((size_t)b*129 + idx)*NN + jt*32 + jq*4;
    dst[0] = 10.0f * fast_tanhf(a0);
    dst[1] = 10.0f * fast_tanhf(a1);
    dst[2] = 10.0f * fast_tanhf(a2);
    dst[3] = 10.0f * fast_tanhf(a3);
  }
}

// ============ K5: sequential sampler (unchanged from round 5) ============
__global__ __launch_bounds__(256) void k_seq(
    const float* __restrict__ l_tab, const float* __restrict__ onode,
    const int* __restrict__ mask_in, const int* __restrict__ id_in,
    float* __restrict__ out)
{
  const int b = blockIdx.x;
  const int tid = threadIdx.x;
  const int wid = tid >> 6;
  const int lane = tid & 63;
  __shared__ float l_s[129*NN];      // 66048 B
  __shared__ float g_a[NN*NN];       // 65536 B
  __shared__ float2 on_s[NN];
  __shared__ int   mask_s[NN];
  __shared__ uint32_t sk0[NN], sk1[NN];

  #pragma unroll
  for (int k = 0; k < 17; ++k){
    const int i4 = tid + 256*k;
    if (i4 < (129*NN)/4)
      ((float4*)l_s)[i4] = ((const float4*)(l_tab + (size_t)b*129*NN))[i4];
  }
  if (tid < NN){
    uint32_t o0, o1; tf2x32(0u, 42u, 0u, (uint32_t)tid, o0, o1);
    sk0[tid] = o0; sk1[tid] = o1;
    mask_s[tid] = mask_in[(size_t)b*NN + tid];
    on_s[tid] = ((const float2*)onode)[b*NN + tid];
  }
  __syncthreads();
  for (int k = 0; k < 64; ++k){
    const int p = tid + 256*k;
    const int i = p >> 7, j = p & 127;
    g_a[p] = jax_gumbel(sk0[i], sk1[i], (uint32_t)(b*NN + j));
  }
  __syncthreads();
  if (wid != 0) return;

  const int id0 = id_in[0];
  const float NEG_INF = -__builtin_huge_valf();
  if (lane == 0){
    out[OFF_INIT + 2*b]     = on_s[0].x;
    out[OFF_INIT + 2*b + 1] = on_s[0].y;
  }
  int prev = 128, cur = 0;
  for (int i = 0; i < NN; ++i){
    float l0 = l_s[prev*NN + lane];
    float l1 = l_s[prev*NN + 64 + lane];
    if (mask_s[lane])      l0 = NEG_INF;
    if (mask_s[64 + lane]) l1 = NEG_INF;
    float y = l0 + g_a[i*NN + lane]; int pj = lane;
    { float yb = l1 + g_a[i*NN + 64 + lane];
      if (yb > y){ y = yb; pj = 64 + lane; } }
    float es = __expf(l0) + __expf(l1);
    CMB_DPP(0xB1); CMB_DPP(0x4E); CMB_DPP(0x124); CMB_DPP(0x128);
    CMB_SWZ16(); CMB_SHF32();
    int bi = pj;
    if (i == 0 && id0 == 0) bi = 0;
    const float lsel = __shfl((bi & 64) ? l1 : l0, bi & 63);
    const float logp = lsel - __logf(es);
    if (lane == 0){
      out[OFF_LOGP + b*NN + i] = logp;
      out[OFF_IDX  + b*NN + i] = (float)bi;
      const float2 pc = on_s[cur];
      const float2 pn = on_s[bi];
      const float dx = pn.x - pc.x, dy = pn.y - pc.y;
      out[OFF_RS + b*NN + i] = sqrtf(dx*dx + dy*dy);
      if (i == NN-1){ out[OFF_LAST + 2*b] = pn.x; out[OFF_LAST + 2*b + 1] = pn.y; }
      mask_s[bi] = 1;
      cur = bi;
    }
    prev = bi;
  }
}

// ================= FALLBACK path kernels (round-4, known-pass) =================
__global__ void k_tmp1(const float* __restrict__ liw, const float* __restrict__ Wr,
                       float* __restrict__ tmp1){
  int e = threadIdx.x;
  float acc = 0.f;
  for (int k = 0; k < 2*EE; ++k) acc = fmaf(liw[k], Wr[(size_t)k*EE + e], acc);
  tmp1[e] = acc;
}

__global__ void k_T1(const float* __restrict__ Wr, const float* __restrict__ Wq,
                     float* __restrict__ T1){
  int r = blockIdx.x, h = threadIdx.x;
  float acc = 0.f;
  for (int e = 0; e < EE; ++e) acc = fmaf(Wr[(size_t)r*EE + e], Wq[(size_t)e*HH + h], acc);
  T1[(size_t)r*HH + h] = acc;
}

__global__ void k_base(const float* __restrict__ lcv, const float* __restrict__ Whbar,
                       const float* __restrict__ bhbar, const float* __restrict__ brest,
                       const float* __restrict__ Wq, const float* __restrict__ bq,
                       float* __restrict__ base){
  __shared__ float sm[EE];
  __shared__ float hb2[EE];
  int b = blockIdx.x, t = threadIdx.x;
  float acc = 0.f;
  const float* p = lcv + (size_t)b*NN*EE + t;
  for (int n = 0; n < NN; ++n) acc += p[(size_t)n*EE];
  sm[t] = acc * 0.0078125f;
  __syncthreads();
  float a2 = 0.f;
  for (int e = 0; e < EE; ++e) a2 = fmaf(sm[e], Whbar[(size_t)e*EE + t], a2);
  hb2[t] = (a2 + bhbar[t]) + brest[t];
  __syncthreads();
  float a3 = 0.f;
  for (int e = 0; e < EE; ++e) a3 = fmaf(hb2[e], Wq[(size_t)e*HH + t], a3);
  base[(size_t)b*HH + t] = a3 + bq[t];
}

__global__ __launch_bounds__(1024, 4) void dec_main(
    const float* __restrict__ lcv, const float* __restrict__ onode,
    const int* __restrict__ mask_in, const int* __restrict__ id_in,
    const float* __restrict__ Wk, const float* __restrict__ bk,
    const float* __restrict__ vvec, const float* __restrict__ T1,
    const float* __restrict__ base, const float* __restrict__ tmp1,
    const float* __restrict__ Wq, float* __restrict__ out)
{
  const int b = blockIdx.x;
  const int tid = threadIdx.x;
  const int wid = tid >> 6;
  const int lane = tid & 63;

  __shared__ __align__(16) float keys_lds[NN*KST];
  __shared__ __align__(16) float q_s[272];
  __shared__ __align__(16) float base_s[HH];
  __shared__ __align__(16) float p1row[HH];
  __shared__ __align__(16) float2 on_s[NN];
  __shared__ float u_s[NN];
  __shared__ float g2_s[2][NN];
  __shared__ int act_s[NN];
  __shared__ int pos_s[NN];
  __shared__ int mask_s[NN];
  __shared__ uint32_t sk0[NN], sk1[NN];
  __shared__ int idx_sh, L_sh;

  const float NEG_INF = -__builtin_huge_valf();
  const int id0 = id_in[0];

  float4 kacc[8], p2acc[8];
  #pragma unroll
  for (int r = 0; r < 8; ++r){
    kacc[r]  = make_float4(0.f,0.f,0.f,0.f);
    p2acc[r] = make_float4(0.f,0.f,0.f,0.f);
  }
  {
    float* sA = keys_lds;
    float* sW = keys_lds + 4608;
    float* sT = keys_lds + 12800;
    for (int ch = 0; ch < 8; ++ch){
      const int e0 = ch << 5;
      __syncthreads();
      {
        const int r = tid >> 3, c = tid & 7;
        const float4 t = ((const float4*)(lcv + ((size_t)b*NN + r)*EE + e0))[c];
        ((float4*)sA)[r*9 + c] = t;
      }
      #pragma unroll
      for (int s = 0; s < 2; ++s){
        const int idx4 = s*1024 + tid;
        const int e = idx4 >> 6, c = idx4 & 63;
        ((float4*)sW)[idx4] = ((const float4*)(Wk + (size_t)(e0+e)*HH))[c];
        ((float4*)sT)[idx4] = ((const float4*)(T1 + (size_t)(EE+e0+e)*HH))[c];
      }
      __syncthreads();
      const float* aRow = sA + (wid << 3)*36;
      for (int e = 0; e < 32; ++e){
        const float4 wv = ((const float4*)sW)[(e<<6) + lane];
        const float4 tv = ((const float4*)sT)[(e<<6) + lane];
        #pragma unroll
        for (int r = 0; r < 8; ++r){
          const float av = aRow[r*36 + e];
          kacc[r].x = fmaf(av, wv.x, kacc[r].x);
          kacc[r].y = fmaf(av, wv.y, kacc[r].y);
          kacc[r].z = fmaf(av, wv.z, kacc[r].z);
          kacc[r].w = fmaf(av, wv.w, kacc[r].w);
          p2acc[r].x = fmaf(av, tv.x, p2acc[r].x);
          p2acc[r].y = fmaf(av, tv.y, p2acc[r].y);
          p2acc[r].z = fmaf(av, tv.z, p2acc[r].z);
          p2acc[r].w = fmaf(av, tv.w, p2acc[r].w);
        }
      }
    }
  }
  __syncthreads();
  {
    const float4 bkv = ((const float4*)bk)[lane];
    const int sphys = ((lane >> 4) << 4) | ((lane & 15) ^ (lane >> 4));
    #pragma unroll
    for (int r = 0; r < 8; ++r){
      const int j = (wid << 3) + r;
      float4 kv = kacc[r];
      kv.x += bkv.x; kv.y += bkv.y; kv.z += bkv.z; kv.w += bkv.w;
      ((float4*)keys_lds)[j*KST4 + sphys] = kv;
    }
  }

  const int grp = tid & 3;
  const int aslot = tid >> 2;

  float4 vreg[16];
  #pragma unroll
  for (int c = 0; c < 16; ++c) vreg[c] = ((const float4*)vvec)[(grp << 4) + c];

  if (tid < HH){
    const float bs = base[(size_t)b*HH + tid];
    base_s[tid] = bs;
    float c0v = 0.f;
    for (int e = 0; e < EE; ++e) c0v = fmaf(tmp1[e], Wq[(size_t)e*HH + tid], c0v);
    q_s[(tid>>6)*68 + (tid&63)] = bs + c0v;
  } else if (tid < HH + NN){
    const int j = tid - HH;
    mask_s[j] = mask_in[(size_t)b*NN + j];
    uint32_t o0,o1; tf2x32(0u, 42u, 0u, (uint32_t)j, o0, o1);
    sk0[j] = o0; sk1[j] = o1;
  } else if (tid == HH + NN){
    out[OFF_INIT + 2*b]     = onode[(size_t)b*NN*2 + 0];
    out[OFF_INIT + 2*b + 1] = onode[(size_t)b*NN*2 + 1];
  } else if (tid >= 512 && tid < 512 + NN){
    on_s[tid - 512] = ((const float2*)onode)[b*NN + (tid - 512)];
  }
  __syncthreads();
  if (tid == 0){
    int L = 0;
    for (int j = 0; j < NN; ++j){
      if (mask_s[j] == 0){ act_s[L] = j; pos_s[j] = L; ++L; }
    }
    L_sh = L;
  }
  if (wid == 15){
    g2_s[0][lane]      = jax_gumbel(sk0[0], sk1[0], (uint32_t)(b*NN + lane));
    g2_s[0][64 + lane] = jax_gumbel(sk0[0], sk1[0], (uint32_t)(b*NN + 64 + lane));
  }

  int cur = 0;

  for (int i = 0; i < NN; ++i){
    __syncthreads();
    const int L = L_sh;
    if (aslot < L){
      const int j = act_s[aslot];
      const int kb4 = j*KST4 + (grp << 4);
      const int qb4 = grp*17;
      float s = 0.f;
      #pragma unroll
      for (int c4 = 0; c4 < 4; ++c4){
        float th[16];
        #pragma unroll
        for (int cc = 0; cc < 4; ++cc){
          const int c = c4*4 + cc;
          const float4 kv = ((const float4*)keys_lds)[kb4 + (c ^ grp)];
          const float4 qv = ((const float4*)q_s)[qb4 + c];
          th[4*cc+0] = fast_tanhf(kv.x + qv.x);
          th[4*cc+1] = fast_tanhf(kv.y + qv.y);
          th[4*cc+2] = fast_tanhf(kv.z + qv.z);
          th[4*cc+3] = fast_tanhf(kv.w + qv.w);
        }
        #pragma unroll
        for (int cc = 0; cc < 4; ++cc){
          const float4 vv = vreg[c4*4 + cc];
          s = fmaf(th[4*cc+0], vv.x, s);
          s = fmaf(th[4*cc+1], vv.y, s);
          s = fmaf(th[4*cc+2], vv.z, s);
          s = fmaf(th[4*cc+3], vv.w, s);
        }
      }
      s += __shfl_xor(s, 1);
      s += __shfl_xor(s, 2);
      if (grp == 0) u_s[j] = s;
    } else if (wid == 15 && i + 1 < NN){
      const int nb = (i + 1) & 1;
      g2_s[nb][lane]      = jax_gumbel(sk0[i+1], sk1[i+1], (uint32_t)(b*NN + lane));
      g2_s[nb][64 + lane] = jax_gumbel(sk0[i+1], sk1[i+1], (uint32_t)(b*NN + 64 + lane));
    }
    __syncthreads();
    float l0 = 0.f, l1 = 0.f; int bi = 0;
    if (wid == 0){
      l0 = 10.0f * fast_tanhf(u_s[lane]);
      l1 = 10.0f * fast_tanhf(u_s[64 + lane]);
      if (mask_s[lane])      l0 = NEG_INF;
      if (mask_s[64 + lane]) l1 = NEG_INF;
      const float y0 = l0 + g2_s[i & 1][lane];
      const float y1 = l1 + g2_s[i & 1][64 + lane];
      float bv;
      if (y1 > y0){ bv = y1; bi = 64 + lane; } else { bv = y0; bi = lane; }
      #pragma unroll
      for (int off = 1; off < 64; off <<= 1){
        const float ov = __shfl_xor(bv, off);
        const int   oi = __shfl_xor(bi, off);
        if (ov > bv || (ov == bv && oi < bi)){ bv = ov; bi = oi; }
      }
      if (i == 0 && id0 == 0) bi = 0;
      if (lane == 0) idx_sh = bi;
    }
    __syncthreads();
    const int idx = idx_sh;
    if (i == 0){
      if (tid < HH){
        const float* arow = lcv + ((size_t)b*NN + idx)*EE;
        float acc = 0.f;
        for (int e = 0; e < EE; ++e) acc = fmaf(arow[e], T1[(size_t)e*HH + tid], acc);
        p1row[tid] = acc;
      }
      __syncthreads();
    }
    if (wid == (idx >> 3)){
      const int r2 = idx & 7;
      float4 pp;
      switch (r2){
        case 0: pp = p2acc[0]; break;
        case 1: pp = p2acc[1]; break;
        case 2: pp = p2acc[2]; break;
        case 3: pp = p2acc[3]; break;
        case 4: pp = p2acc[4]; break;
        case 5: pp = p2acc[5]; break;
        case 6: pp = p2acc[6]; break;
        default: pp = p2acc[7]; break;
      }
      const float4 b4 = ((const float4*)base_s)[lane];
      const float4 p4 = ((const float4*)p1row)[lane];
      float4 nq;
      nq.x = (b4.x + p4.x) + pp.x;
      nq.y = (b4.y + p4.y) + pp.y;
      nq.z = (b4.z + p4.z) + pp.z;
      nq.w = (b4.w + p4.w) + pp.w;
      ((float4*)q_s)[((lane >> 4)*17) + (lane & 15)] = nq;
    }
    if (wid == 0){
      float es = __expf(l0) + __expf(l1);
      #pragma unroll
      for (int off = 1; off < 64; off <<= 1) es += __shfl_xor(es, off);
      const float lown = (bi >= 64) ? l1 : l0;
      const float lsel = __shfl(lown, bi & 63);
      const float logp = lsel - __logf(es);
      if (lane == 0){
        out[OFF_LOGP + b*NN + i] = logp;
        out[OFF_IDX  + b*NN + i] = (float)bi;
        const float2 pc = on_s[cur];
        const float2 pn = on_s[bi];
        const float dx = pn.x - pc.x, dy = pn.y - pc.y;
        out[OFF_RS + b*NN + i] = sqrtf(dx*dx + dy*dy);
        if (i == NN-1){ out[OFF_LAST + 2*b] = pn.x; out[OFF_LAST + 2*b + 1] = pn.y; }
        cur = bi;
        if (mask_s[bi] == 0){
          mask_s[bi] = 1;
          const int p = pos_s[bi];
          const int Lm = L_sh - 1;
          const int last = act_s[Lm];
          act_s[p] = last;
          pos_s[last] = p;
          L_sh = Lm;
        }
      }
    }
  }
}

extern "C" void kernel_launch(void* const* d_in, const int* in_sizes, int n_in,
                              void* d_out, int out_size, void* d_ws, size_t ws_size,
                              hipStream_t stream){
  const float* lcv   = (const float*)d_in[0];
  const float* onode = (const float*)d_in[1];
  const int*   mask  = (const int*)d_in[2];
  const int*   id    = (const int*)d_in[3];
  const float* liw   = (const float*)d_in[4];
  const float* Whbar = (const float*)d_in[5];
  const float* bhbar = (const float*)d_in[6];
  const float* Wrest = (const float*)d_in[7];
  const float* brest = (const float*)d_in[8];
  const float* Wk    = (const float*)d_in[9];
  const float* bk    = (const float*)d_in[10];
  const float* Wq    = (const float*)d_in[11];
  const float* bq    = (const float*)d_in[12];
  const float* vv    = (const float*)d_in[13];

  float* ws  = (float*)d_ws;
  float* out = (float*)d_out;

  const size_t NEED_BYTES = 21267200ull * 4ull;   // 81.1 MB

  if (ws_size >= NEED_BYTES){
    float* T1   = ws;                 // 131072
    float* base = ws + 131072;        // 65536
    float* c0   = ws + 196864;        // 256
    float* qb   = ws + 197120;        // 65536
    float* keys = ws + 262912;        // 8388608
    float* P2   = ws + 8651520;       // 8388608
    float* ltab = ws + 17040128;      // 4227072

    hipLaunchKernelGGL(k_pre,    dim3(769),  dim3(256),  0, stream,
                       liw, Wrest, Wq, lcv, Whbar, bhbar, brest, bq, c0, T1, base);
    hipLaunchKernelGGL(k_keysP2, dim3(256),  dim3(1024), 0, stream,
                       lcv, Wk, T1, bk, base, c0, vv, keys, P2, ltab);
    hipLaunchKernelGGL(k_idx0qb, dim3(256),  dim3(256),  0, stream,
                       ltab, mask, id, lcv, T1, base, qb);
    hipLaunchKernelGGL(k_tab,    dim3(1024), dim3(256),  0, stream, keys, P2, qb, vv, ltab);
    hipLaunchKernelGGL(k_seq,    dim3(256),  dim3(256),  0, stream, ltab, onode, mask, id, out);
  } else {
    // fallback: round-4 path (known-pass)
    float* T1   = ws;            // 512*256
    float* base = ws + 131072;   // 256*256
    float* tmp1 = ws + 196608;   // 256

    hipLaunchKernelGGL(k_tmp1, dim3(1),   dim3(256), 0, stream, liw, Wrest, tmp1);
    hipLaunchKernelGGL(k_T1,   dim3(512), dim3(256), 0, stream, Wrest, Wq, T1);
    hipLaunchKernelGGL(k_base, dim3(256), dim3(256), 0, stream, lcv, Whbar, bhbar, brest, Wq, bq, base);
    hipLaunchKernelGGL(dec_main, dim3(256), dim3(1024), 0, stream,
                       lcv, onode, mask, id, Wk, bk, vv, T1, base, tmp1, Wq, out);
  }
}

// Round 7
// 453.082 us; speedup vs baseline: 1.7773x; 1.1682x over previous
//
#include <hip/hip_runtime.h>
#include <stdint.h>
#include <math.h>

#define NN 128
#define EE 256
#define HH 256

#define OFF_LOGP 0
#define OFF_IDX  32768
#define OFF_INIT 65536
#define OFF_LAST 66048
#define OFF_RS   66560

// keys row stride in floats / float4 slots (padded: 260 = 65*4) -- fallback path
#define KST  260
#define KST4 65

__device__ __forceinline__ uint32_t rotl32_(uint32_t x, int d){ return (x<<d)|(x>>(32-d)); }

// Threefry-2x32, 20 rounds, JAX key schedule (bit-identical to rounds 1-6)
__device__ __forceinline__ void tf2x32(uint32_t k0, uint32_t k1, uint32_t x0, uint32_t x1,
                                       uint32_t& o0, uint32_t& o1){
  uint32_t k2 = k0 ^ k1 ^ 0x1BD11BDAu;
  x0 += k0; x1 += k1;
#define TF_RND(r) { x0 += x1; x1 = rotl32_(x1,(r)); x1 ^= x0; }
  TF_RND(13) TF_RND(15) TF_RND(26) TF_RND(6)
  x0 += k1; x1 += k2 + 1u;
  TF_RND(17) TF_RND(29) TF_RND(16) TF_RND(24)
  x0 += k2; x1 += k0 + 2u;
  TF_RND(13) TF_RND(15) TF_RND(26) TF_RND(6)
  x0 += k0; x1 += k1 + 3u;
  TF_RND(17) TF_RND(29) TF_RND(16) TF_RND(24)
  x0 += k1; x1 += k2 + 4u;
  TF_RND(13) TF_RND(15) TF_RND(26) TF_RND(6)
  x0 += k2; x1 += k0 + 5u;
#undef TF_RND
  o0 = x0; o1 = x1;
}

// Refined fast tanh (rounds 4-6, passed): ~0.5 ulp division
__device__ __forceinline__ float fast_tanhf(float x){
  float ax = __builtin_fabsf(x);
  float E = __builtin_amdgcn_exp2f(ax * -2.885390081777927f);  // 2^(-2*log2(e)*|x|)
  float num = 1.0f - E;
  float den = 1.0f + E;
  float inv = __builtin_amdgcn_rcpf(den);
  inv = fmaf(fmaf(-den, inv, 1.0f), inv, inv);   // Newton refine
  float r = num * inv;
  r = fmaf(fmaf(-den, r, num), inv, r);          // residual correction
  return __builtin_copysignf(r, x);
}

// k_tab inner tanh on PRE-SCALED input xs = x * 2*log2(e):
// tanh(x) = 1 - 2/(1 + e^{2x}) = fmaf(-2, rcp(1+exp2(xs)), 1).
// 4 full-rate + 2 trans ops vs 8+2 for the abs/copysign form. ~2 ulp abs err,
// saturates exactly (xs->+inf: rcp(inf)=0 -> 1; xs->-inf: rcp(1)=1 -> -1).
__device__ __forceinline__ float tanh_pre(float xs){
  float E = __builtin_amdgcn_exp2f(xs);
  return fmaf(-2.0f, __builtin_amdgcn_rcpf(1.0f + E), 1.0f);
}

// jax.random.gumbel element — bit-identical to rounds 1-6 (feeds argmax: IEEE logf)
__device__ __forceinline__ float jax_gumbel(uint32_t k0, uint32_t k1, uint32_t t){
  uint32_t o0, o1, bits;
  tf2x32(k0, k1, 0u, t, o0, o1);
  bits = o0 ^ o1;
  float u = __uint_as_float((bits >> 9) | 0x3f800000u) - 1.0f;
  const float kTiny = 1.17549435e-38f;
  u = fmaxf(kTiny, u + kTiny);
  return -logf(-logf(u));
}

// Wave-wide argmax(+sum) reduce: quad_perm xor1/xor2 + row_ror4/8 (DPP) +
// ds_swizzle xor16 + shfl xor32. Associative w/ smallest-index tie-break.
#define CMB_DPP(CTRL) { \
  float ny_ = __int_as_float(__builtin_amdgcn_mov_dpp(__float_as_int(y), (CTRL), 0xf, 0xf, false)); \
  int   nj_ = __builtin_amdgcn_mov_dpp(pj, (CTRL), 0xf, 0xf, false); \
  float ne_ = __int_as_float(__builtin_amdgcn_mov_dpp(__float_as_int(es), (CTRL), 0xf, 0xf, false)); \
  es += ne_; \
  if (ny_ > y || (ny_ == y && nj_ < pj)){ y = ny_; pj = nj_; } }
#define CMB_SWZ16() { \
  float ny_ = __int_as_float(__builtin_amdgcn_ds_swizzle(__float_as_int(y), 0x401F)); \
  int   nj_ = __builtin_amdgcn_ds_swizzle(pj, 0x401F); \
  float ne_ = __int_as_float(__builtin_amdgcn_ds_swizzle(__float_as_int(es), 0x401F)); \
  es += ne_; \
  if (ny_ > y || (ny_ == y && nj_ < pj)){ y = ny_; pj = nj_; } }
#define CMB_SHF32() { \
  float ny_ = __shfl_xor(y, 32); \
  int   nj_ = __shfl_xor(pj, 32); \
  float ne_ = __shfl_xor(es, 32); \
  es += ne_; \
  if (ny_ > y || (ny_ == y && nj_ < pj)){ y = ny_; pj = nj_; } }

// ============ K1: fused precompute (block 0: tmp1+c0 | 1..512: T1 | 513..768: base) ============
__global__ __launch_bounds__(256) void k_pre(
    const float* __restrict__ liw, const float* __restrict__ Wr,
    const float* __restrict__ Wq, const float* __restrict__ lcv,
    const float* __restrict__ Whbar, const float* __restrict__ bhbar,
    const float* __restrict__ brest, const float* __restrict__ bq,
    float* __restrict__ c0, float* __restrict__ T1, float* __restrict__ base)
{
  __shared__ float sbuf[512];
  const int bid = blockIdx.x;
  const int t = threadIdx.x;
  if (bid == 0){
    float acc = 0.f;
    for (int k = 0; k < 2*EE; ++k) acc = fmaf(liw[k], Wr[(size_t)k*EE + t], acc);
    sbuf[t] = acc;
    __syncthreads();
    float c = 0.f;
    for (int e = 0; e < EE; ++e) c = fmaf(sbuf[e], Wq[(size_t)e*HH + t], c);
    c0[t] = c;
  } else if (bid <= 512){
    const int r = bid - 1;
    float acc = 0.f;
    for (int e = 0; e < EE; ++e) acc = fmaf(Wr[(size_t)r*EE + e], Wq[(size_t)e*HH + t], acc);
    T1[(size_t)r*HH + t] = acc;
  } else {
    const int b = bid - 513;
    float* sm  = sbuf;
    float* hb2 = sbuf + 256;
    float acc = 0.f;
    const float* p = lcv + (size_t)b*NN*EE + t;
    for (int n = 0; n < NN; ++n) acc += p[(size_t)n*EE];
    sm[t] = acc * 0.0078125f;
    __syncthreads();
    float a2 = 0.f;
    for (int e = 0; e < EE; ++e) a2 = fmaf(sm[e], Whbar[(size_t)e*EE + t], a2);
    hb2[t] = (a2 + bhbar[t]) + brest[t];
    __syncthreads();
    float a3 = 0.f;
    for (int e = 0; e < EE; ++e) a3 = fmaf(hb2[e], Wq[(size_t)e*HH + t], a3);
    base[(size_t)b*HH + t] = a3 + bq[t];
  }
}

// ============ K2: keys/P2 GEMM + fused l0 row (unchanged from round 6) ============
__global__ __launch_bounds__(1024) void k_keysP2(
    const float* __restrict__ lcv, const float* __restrict__ Wk,
    const float* __restrict__ T1, const float* __restrict__ bk,
    const float* __restrict__ base, const float* __restrict__ c0,
    const float* __restrict__ vvec,
    float* __restrict__ keysg, float* __restrict__ P2g, float* __restrict__ ltab)
{
  const int b = blockIdx.x, tid = threadIdx.x, wid = tid >> 6, lane = tid & 63;
  __shared__ __align__(16) float sbuf[20992];   // sA[128][36] + sW[32][256] + sT[32][256]
  __shared__ __align__(16) float q0s[EE];
  __shared__ __align__(16) float vs[EE];
  float* sA = sbuf;
  float* sW = sbuf + 4608;
  float* sT = sbuf + 12800;
  if (tid < 64){
    float4 bs = ((const float4*)(base + (size_t)b*HH))[tid];
    const float4 cc = ((const float4*)c0)[tid];
    bs.x += cc.x; bs.y += cc.y; bs.z += cc.z; bs.w += cc.w;
    ((float4*)q0s)[tid] = bs;
    ((float4*)vs)[tid]  = ((const float4*)vvec)[tid];
  }
  float4 kacc[8], p2acc[8];
  #pragma unroll
  for (int r = 0; r < 8; ++r){
    kacc[r]  = make_float4(0.f,0.f,0.f,0.f);
    p2acc[r] = make_float4(0.f,0.f,0.f,0.f);
  }
  for (int ch = 0; ch < 8; ++ch){
    const int e0 = ch << 5;
    __syncthreads();
    {
      const int r = tid >> 3, c = tid & 7;
      const float4 t = ((const float4*)(lcv + ((size_t)b*NN + r)*EE + e0))[c];
      ((float4*)sA)[r*9 + c] = t;
    }
    #pragma unroll
    for (int s = 0; s < 2; ++s){
      const int idx4 = s*1024 + tid;
      const int e = idx4 >> 6, c = idx4 & 63;
      ((float4*)sW)[idx4] = ((const float4*)(Wk + (size_t)(e0+e)*HH))[c];
      ((float4*)sT)[idx4] = ((const float4*)(T1 + (size_t)(EE+e0+e)*HH))[c];
    }
    __syncthreads();
    const float* aRow = sA + (wid << 3)*36;
    for (int e = 0; e < 32; ++e){
      const float4 wv = ((const float4*)sW)[(e<<6) + lane];
      const float4 tv = ((const float4*)sT)[(e<<6) + lane];
      #pragma unroll
      for (int r = 0; r < 8; ++r){
        const float av = aRow[r*36 + e];
        kacc[r].x = fmaf(av, wv.x, kacc[r].x);
        kacc[r].y = fmaf(av, wv.y, kacc[r].y);
        kacc[r].z = fmaf(av, wv.z, kacc[r].z);
        kacc[r].w = fmaf(av, wv.w, kacc[r].w);
        p2acc[r].x = fmaf(av, tv.x, p2acc[r].x);
        p2acc[r].y = fmaf(av, tv.y, p2acc[r].y);
        p2acc[r].z = fmaf(av, tv.z, p2acc[r].z);
        p2acc[r].w = fmaf(av, tv.w, p2acc[r].w);
      }
    }
  }
  const float4 bkv = ((const float4*)bk)[lane];
  const float4 qv0 = ((const float4*)q0s)[lane];
  const float4 vv0 = ((const float4*)vs)[lane];
  #pragma unroll
  for (int r = 0; r < 8; ++r){
    const int j = (wid << 3) + r;
    float4 kv = kacc[r];
    kv.x += bkv.x; kv.y += bkv.y; kv.z += bkv.z; kv.w += bkv.w;
    ((float4*)(keysg + ((size_t)b*NN + j)*EE))[lane] = kv;
    ((float4*)(P2g   + ((size_t)b*NN + j)*EE))[lane] = p2acc[r];
    float p = 0.f;
    p = fmaf(fast_tanhf(kv.x + qv0.x), vv0.x, p);
    p = fmaf(fast_tanhf(kv.y + qv0.y), vv0.y, p);
    p = fmaf(fast_tanhf(kv.z + qv0.z), vv0.z, p);
    p = fmaf(fast_tanhf(kv.w + qv0.w), vv0.w, p);
    #pragma unroll
    for (int off = 1; off < 64; off <<= 1) p += __shfl_xor(p, off);
    if (lane == 0) ltab[((size_t)b*129 + 128)*NN + j] = 10.0f * fast_tanhf(p);
  }
}

// ============ K3: fused idx0 + qb GEMV (unchanged from round 6) ============
__global__ __launch_bounds__(256) void k_idx0qb(
    const float* __restrict__ ltab, const int* __restrict__ mask_in,
    const int* __restrict__ id_in, const float* __restrict__ lcv,
    const float* __restrict__ T1, const float* __restrict__ base,
    float* __restrict__ qb)
{
  const int b = blockIdx.x, t = threadIdx.x, lane = t & 63;
  __shared__ int idx_sh;
  if (t < 64){
    const float NEG_INF = -__builtin_huge_valf();
    float l0 = ltab[((size_t)b*129 + 128)*NN + lane];
    float l1 = ltab[((size_t)b*129 + 128)*NN + 64 + lane];
    if (mask_in[(size_t)b*NN + lane])      l0 = NEG_INF;
    if (mask_in[(size_t)b*NN + 64 + lane]) l1 = NEG_INF;
    uint32_t k0, k1; tf2x32(0u, 42u, 0u, 0u, k0, k1);
    const float g0 = jax_gumbel(k0, k1, (uint32_t)(b*NN + lane));
    const float g1 = jax_gumbel(k0, k1, (uint32_t)(b*NN + 64 + lane));
    float y = l0 + g0; int pj = lane;
    { float yb = l1 + g1; if (yb > y){ y = yb; pj = 64 + lane; } }
    float es = 0.f;   // unused
    CMB_DPP(0xB1); CMB_DPP(0x4E); CMB_DPP(0x124); CMB_DPP(0x128);
    CMB_SWZ16(); CMB_SHF32();
    int bi = pj;
    if (id_in[0] == 0) bi = 0;
    if (lane == 0) idx_sh = bi;
  }
  __syncthreads();
  const int i0 = idx_sh;
  const float* arow = lcv + ((size_t)b*NN + i0)*EE;
  float acc = 0.f;
  #pragma unroll 4
  for (int e = 0; e < EE; ++e) acc = fmaf(arow[e], T1[(size_t)e*HH + t], acc);
  qb[(size_t)b*HH + t] = base[(size_t)b*HH + t] + acc;
}

// ============ K4: the big table (slimmed inner loop) ============
// l_tab[b][idx][j] = 10*tanh(sum_h tanh_pre(ckeys[j,h] + cQ2[idx,h]) * v[h])
// where ckeys = keys*c, cQ2 = (P2+qb)*c, c = 2*log2(e).
__global__ __launch_bounds__(256) void k_tab(
    const float* __restrict__ keysg, const float* __restrict__ P2g,
    const float* __restrict__ qb, const float* __restrict__ vvec,
    float* __restrict__ l_tab)
{
  const int b  = blockIdx.x >> 2;
  const int jt = blockIdx.x & 3;
  const int t = threadIdx.x;
  const float CSC = 2.885390081777927f;            // 2*log2(e)
  __shared__ __align__(16) float skeys[32*65*4];   // [32 rows][65 f4], xor-swizzled, *CSC
  __shared__ __align__(16) float sQ2[32*65*4];     // [32 rows][65 f4], (P2+qb)*CSC
  __shared__ __align__(16) float sv[EE];
  __shared__ __align__(16) float sqbc[EE];         // qb*CSC

  #pragma unroll
  for (int k = 0; k < 8; ++k){
    const int idx4 = t + 256*k;                // 0..2047
    const int row = idx4 >> 6, hc = idx4 & 63;
    float4 kv = ((const float4*)(keysg + ((size_t)b*NN + jt*32 + row)*EE))[hc];
    kv.x *= CSC; kv.y *= CSC; kv.z *= CSC; kv.w *= CSC;
    ((float4*)skeys)[row*65 + (hc ^ ((row >> 2) & 7))] = kv;
  }
  if (t < 64){
    ((float4*)sv)[t]  = ((const float4*)vvec)[t];
    float4 qv = ((const float4*)(qb + (size_t)b*HH))[t];
    qv.x *= CSC; qv.y *= CSC; qv.z *= CSC; qv.w *= CSC;
    ((float4*)sqbc)[t] = qv;
  }
  const int jq = t & 7;       // j-quad: j = jq*4 + jj
  const int iq = t >> 3;      // idx within 32-chunk

  // prefetch P2 chunk for ib=0 into registers
  float4 pr[8];
  #pragma unroll
  for (int k = 0; k < 8; ++k){
    const int idx4 = t + 256*k;
    const int row = idx4 >> 6, hc = idx4 & 63;
    pr[k] = ((const float4*)(P2g + ((size_t)b*NN + row)*EE))[hc];
  }

  for (int ib = 0; ib < 4; ++ib){
    __syncthreads();
    #pragma unroll
    for (int k = 0; k < 8; ++k){
      const int idx4 = t + 256*k;
      const int row = idx4 >> 6, hc = idx4 & 63;
      const float4 qv = ((const float4*)sqbc)[hc];
      float4 pv;
      pv.x = fmaf(pr[k].x, CSC, qv.x);
      pv.y = fmaf(pr[k].y, CSC, qv.y);
      pv.z = fmaf(pr[k].z, CSC, qv.z);
      pv.w = fmaf(pr[k].w, CSC, qv.w);
      ((float4*)sQ2)[row*65 + hc] = pv;
    }
    if (ib + 1 < 4){   // issue next chunk's loads; complete under compute
      #pragma unroll
      for (int k = 0; k < 8; ++k){
        const int idx4 = t + 256*k;
        const int row = idx4 >> 6, hc = idx4 & 63;
        pr[k] = ((const float4*)(P2g + ((size_t)b*NN + (ib+1)*32 + row)*EE))[hc];
      }
    }
    __syncthreads();
    float a0 = 0.f, a1 = 0.f, a2 = 0.f, a3 = 0.f;
    #pragma unroll 2
    for (int hc = 0; hc < 64; ++hc){
      const float4 qv = ((const float4*)sQ2)[iq*65 + hc];
      const float4 vv = ((const float4*)sv)[hc];
      const int hx = hc ^ jq;                  // matches write swizzle ((row>>2)&7)=jq
      const float4 k0 = ((const float4*)skeys)[(jq*4 + 0)*65 + hx];
      const float4 k1 = ((const float4*)skeys)[(jq*4 + 1)*65 + hx];
      const float4 k2 = ((const float4*)skeys)[(jq*4 + 2)*65 + hx];
      const float4 k3 = ((const float4*)skeys)[(jq*4 + 3)*65 + hx];
      a0 = fmaf(tanh_pre(k0.x + qv.x), vv.x, a0);
      a0 = fmaf(tanh_pre(k0.y + qv.y), vv.y, a0);
      a0 = fmaf(tanh_pre(k0.z + qv.z), vv.z, a0);
      a0 = fmaf(tanh_pre(k0.w + qv.w), vv.w, a0);
      a1 = fmaf(tanh_pre(k1.x + qv.x), vv.x, a1);
      a1 = fmaf(tanh_pre(k1.y + qv.y), vv.y, a1);
      a1 = fmaf(tanh_pre(k1.z + qv.z), vv.z, a1);
      a1 = fmaf(tanh_pre(k1.w + qv.w), vv.w, a1);
      a2 = fmaf(tanh_pre(k2.x + qv.x), vv.x, a2);
      a2 = fmaf(tanh_pre(k2.y + qv.y), vv.y, a2);
      a2 = fmaf(tanh_pre(k2.z + qv.z), vv.z, a2);
      a2 = fmaf(tanh_pre(k2.w + qv.w), vv.w, a2);
      a3 = fmaf(tanh_pre(k3.x + qv.x), vv.x, a3);
      a3 = fmaf(tanh_pre(k3.y + qv.y), vv.y, a3);
      a3 = fmaf(tanh_pre(k3.z + qv.z), vv.z, a3);
      a3 = fmaf(tanh_pre(k3.w + qv.w), vv.w, a3);
    }
    const int idx = ib*32 + iq;
    float* dst = l_tab + ((size_t)b*129 + idx)*NN + jt*32 + jq*4;
    dst[0] = 10.0f * fast_tanhf(a0);
    dst[1] = 10.0f * fast_tanhf(a1);
    dst[2] = 10.0f * fast_tanhf(a2);
    dst[3] = 10.0f * fast_tanhf(a3);
  }
}

// ============ K5: sequential sampler (unchanged from round 6) ============
__global__ __launch_bounds__(256) void k_seq(
    const float* __restrict__ l_tab, const float* __restrict__ onode,
    const int* __restrict__ mask_in, const int* __restrict__ id_in,
    float* __restrict__ out)
{
  const int b = blockIdx.x;
  const int tid = threadIdx.x;
  const int wid = tid >> 6;
  const int lane = tid & 63;
  __shared__ float l_s[129*NN];      // 66048 B
  __shared__ float g_a[NN*NN];       // 65536 B
  __shared__ float2 on_s[NN];
  __shared__ int   mask_s[NN];
  __shared__ uint32_t sk0[NN], sk1[NN];

  #pragma unroll
  for (int k = 0; k < 17; ++k){
    const int i4 = tid + 256*k;
    if (i4 < (129*NN)/4)
      ((float4*)l_s)[i4] = ((const float4*)(l_tab + (size_t)b*129*NN))[i4];
  }
  if (tid < NN){
    uint32_t o0, o1; tf2x32(0u, 42u, 0u, (uint32_t)tid, o0, o1);
    sk0[tid] = o0; sk1[tid] = o1;
    mask_s[tid] = mask_in[(size_t)b*NN + tid];
    on_s[tid] = ((const float2*)onode)[b*NN + tid];
  }
  __syncthreads();
  for (int k = 0; k < 64; ++k){
    const int p = tid + 256*k;
    const int i = p >> 7, j = p & 127;
    g_a[p] = jax_gumbel(sk0[i], sk1[i], (uint32_t)(b*NN + j));
  }
  __syncthreads();
  if (wid != 0) return;

  const int id0 = id_in[0];
  const float NEG_INF = -__builtin_huge_valf();
  if (lane == 0){
    out[OFF_INIT + 2*b]     = on_s[0].x;
    out[OFF_INIT + 2*b + 1] = on_s[0].y;
  }
  int prev = 128, cur = 0;
  for (int i = 0; i < NN; ++i){
    float l0 = l_s[prev*NN + lane];
    float l1 = l_s[prev*NN + 64 + lane];
    if (mask_s[lane])      l0 = NEG_INF;
    if (mask_s[64 + lane]) l1 = NEG_INF;
    float y = l0 + g_a[i*NN + lane]; int pj = lane;
    { float yb = l1 + g_a[i*NN + 64 + lane];
      if (yb > y){ y = yb; pj = 64 + lane; } }
    float es = __expf(l0) + __expf(l1);
    CMB_DPP(0xB1); CMB_DPP(0x4E); CMB_DPP(0x124); CMB_DPP(0x128);
    CMB_SWZ16(); CMB_SHF32();
    int bi = pj;
    if (i == 0 && id0 == 0) bi = 0;
    const float lsel = __shfl((bi & 64) ? l1 : l0, bi & 63);
    const float logp = lsel - __logf(es);
    if (lane == 0){
      out[OFF_LOGP + b*NN + i] = logp;
      out[OFF_IDX  + b*NN + i] = (float)bi;
      const float2 pc = on_s[cur];
      const float2 pn = on_s[bi];
      const float dx = pn.x - pc.x, dy = pn.y - pc.y;
      out[OFF_RS + b*NN + i] = sqrtf(dx*dx + dy*dy);
      if (i == NN-1){ out[OFF_LAST + 2*b] = pn.x; out[OFF_LAST + 2*b + 1] = pn.y; }
      mask_s[bi] = 1;
      cur = bi;
    }
    prev = bi;
  }
}

// ================= FALLBACK path kernels (round-4, known-pass) =================
__global__ void k_tmp1(const float* __restrict__ liw, const float* __restrict__ Wr,
                       float* __restrict__ tmp1){
  int e = threadIdx.x;
  float acc = 0.f;
  for (int k = 0; k < 2*EE; ++k) acc = fmaf(liw[k], Wr[(size_t)k*EE + e], acc);
  tmp1[e] = acc;
}

__global__ void k_T1(const float* __restrict__ Wr, const float* __restrict__ Wq,
                     float* __restrict__ T1){
  int r = blockIdx.x, h = threadIdx.x;
  float acc = 0.f;
  for (int e = 0; e < EE; ++e) acc = fmaf(Wr[(size_t)r*EE + e], Wq[(size_t)e*HH + h], acc);
  T1[(size_t)r*HH + h] = acc;
}

__global__ void k_base(const float* __restrict__ lcv, const float* __restrict__ Whbar,
                       const float* __restrict__ bhbar, const float* __restrict__ brest,
                       const float* __restrict__ Wq, const float* __restrict__ bq,
                       float* __restrict__ base){
  __shared__ float sm[EE];
  __shared__ float hb2[EE];
  int b = blockIdx.x, t = threadIdx.x;
  float acc = 0.f;
  const float* p = lcv + (size_t)b*NN*EE + t;
  for (int n = 0; n < NN; ++n) acc += p[(size_t)n*EE];
  sm[t] = acc * 0.0078125f;
  __syncthreads();
  float a2 = 0.f;
  for (int e = 0; e < EE; ++e) a2 = fmaf(sm[e], Whbar[(size_t)e*EE + t], a2);
  hb2[t] = (a2 + bhbar[t]) + brest[t];
  __syncthreads();
  float a3 = 0.f;
  for (int e = 0; e < EE; ++e) a3 = fmaf(hb2[e], Wq[(size_t)e*HH + t], a3);
  base[(size_t)b*HH + t] = a3 + bq[t];
}

__global__ __launch_bounds__(1024, 4) void dec_main(
    const float* __restrict__ lcv, const float* __restrict__ onode,
    const int* __restrict__ mask_in, const int* __restrict__ id_in,
    const float* __restrict__ Wk, const float* __restrict__ bk,
    const float* __restrict__ vvec, const float* __restrict__ T1,
    const float* __restrict__ base, const float* __restrict__ tmp1,
    const float* __restrict__ Wq, float* __restrict__ out)
{
  const int b = blockIdx.x;
  const int tid = threadIdx.x;
  const int wid = tid >> 6;
  const int lane = tid & 63;

  __shared__ __align__(16) float keys_lds[NN*KST];
  __shared__ __align__(16) float q_s[272];
  __shared__ __align__(16) float base_s[HH];
  __shared__ __align__(16) float p1row[HH];
  __shared__ __align__(16) float2 on_s[NN];
  __shared__ float u_s[NN];
  __shared__ float g2_s[2][NN];
  __shared__ int act_s[NN];
  __shared__ int pos_s[NN];
  __shared__ int mask_s[NN];
  __shared__ uint32_t sk0[NN], sk1[NN];
  __shared__ int idx_sh, L_sh;

  const float NEG_INF = -__builtin_huge_valf();
  const int id0 = id_in[0];

  float4 kacc[8], p2acc[8];
  #pragma unroll
  for (int r = 0; r < 8; ++r){
    kacc[r]  = make_float4(0.f,0.f,0.f,0.f);
    p2acc[r] = make_float4(0.f,0.f,0.f,0.f);
  }
  {
    float* sA = keys_lds;
    float* sW = keys_lds + 4608;
    float* sT = keys_lds + 12800;
    for (int ch = 0; ch < 8; ++ch){
      const int e0 = ch << 5;
      __syncthreads();
      {
        const int r = tid >> 3, c = tid & 7;
        const float4 t = ((const float4*)(lcv + ((size_t)b*NN + r)*EE + e0))[c];
        ((float4*)sA)[r*9 + c] = t;
      }
      #pragma unroll
      for (int s = 0; s < 2; ++s){
        const int idx4 = s*1024 + tid;
        const int e = idx4 >> 6, c = idx4 & 63;
        ((float4*)sW)[idx4] = ((const float4*)(Wk + (size_t)(e0+e)*HH))[c];
        ((float4*)sT)[idx4] = ((const float4*)(T1 + (size_t)(EE+e0+e)*HH))[c];
      }
      __syncthreads();
      const float* aRow = sA + (wid << 3)*36;
      for (int e = 0; e < 32; ++e){
        const float4 wv = ((const float4*)sW)[(e<<6) + lane];
        const float4 tv = ((const float4*)sT)[(e<<6) + lane];
        #pragma unroll
        for (int r = 0; r < 8; ++r){
          const float av = aRow[r*36 + e];
          kacc[r].x = fmaf(av, wv.x, kacc[r].x);
          kacc[r].y = fmaf(av, wv.y, kacc[r].y);
          kacc[r].z = fmaf(av, wv.z, kacc[r].z);
          kacc[r].w = fmaf(av, wv.w, kacc[r].w);
          p2acc[r].x = fmaf(av, tv.x, p2acc[r].x);
          p2acc[r].y = fmaf(av, tv.y, p2acc[r].y);
          p2acc[r].z = fmaf(av, tv.z, p2acc[r].z);
          p2acc[r].w = fmaf(av, tv.w, p2acc[r].w);
        }
      }
    }
  }
  __syncthreads();
  {
    const float4 bkv = ((const float4*)bk)[lane];
    const int sphys = ((lane >> 4) << 4) | ((lane & 15) ^ (lane >> 4));
    #pragma unroll
    for (int r = 0; r < 8; ++r){
      const int j = (wid << 3) + r;
      float4 kv = kacc[r];
      kv.x += bkv.x; kv.y += bkv.y; kv.z += bkv.z; kv.w += bkv.w;
      ((float4*)keys_lds)[j*KST4 + sphys] = kv;
    }
  }

  const int grp = tid & 3;
  const int aslot = tid >> 2;

  float4 vreg[16];
  #pragma unroll
  for (int c = 0; c < 16; ++c) vreg[c] = ((const float4*)vvec)[(grp << 4) + c];

  if (tid < HH){
    const float bs = base[(size_t)b*HH + tid];
    base_s[tid] = bs;
    float c0v = 0.f;
    for (int e = 0; e < EE; ++e) c0v = fmaf(tmp1[e], Wq[(size_t)e*HH + tid], c0v);
    q_s[(tid>>6)*68 + (tid&63)] = bs + c0v;
  } else if (tid < HH + NN){
    const int j = tid - HH;
    mask_s[j] = mask_in[(size_t)b*NN + j];
    uint32_t o0,o1; tf2x32(0u, 42u, 0u, (uint32_t)j, o0, o1);
    sk0[j] = o0; sk1[j] = o1;
  } else if (tid == HH + NN){
    out[OFF_INIT + 2*b]     = onode[(size_t)b*NN*2 + 0];
    out[OFF_INIT + 2*b + 1] = onode[(size_t)b*NN*2 + 1];
  } else if (tid >= 512 && tid < 512 + NN){
    on_s[tid - 512] = ((const float2*)onode)[b*NN + (tid - 512)];
  }
  __syncthreads();
  if (tid == 0){
    int L = 0;
    for (int j = 0; j < NN; ++j){
      if (mask_s[j] == 0){ act_s[L] = j; pos_s[j] = L; ++L; }
    }
    L_sh = L;
  }
  if (wid == 15){
    g2_s[0][lane]      = jax_gumbel(sk0[0], sk1[0], (uint32_t)(b*NN + lane));
    g2_s[0][64 + lane] = jax_gumbel(sk0[0], sk1[0], (uint32_t)(b*NN + 64 + lane));
  }

  int cur = 0;

  for (int i = 0; i < NN; ++i){
    __syncthreads();
    const int L = L_sh;
    if (aslot < L){
      const int j = act_s[aslot];
      const int kb4 = j*KST4 + (grp << 4);
      const int qb4 = grp*17;
      float s = 0.f;
      #pragma unroll
      for (int c4 = 0; c4 < 4; ++c4){
        float th[16];
        #pragma unroll
        for (int cc = 0; cc < 4; ++cc){
          const int c = c4*4 + cc;
          const float4 kv = ((const float4*)keys_lds)[kb4 + (c ^ grp)];
          const float4 qv = ((const float4*)q_s)[qb4 + c];
          th[4*cc+0] = fast_tanhf(kv.x + qv.x);
          th[4*cc+1] = fast_tanhf(kv.y + qv.y);
          th[4*cc+2] = fast_tanhf(kv.z + qv.z);
          th[4*cc+3] = fast_tanhf(kv.w + qv.w);
        }
        #pragma unroll
        for (int cc = 0; cc < 4; ++cc){
          const float4 vv = vreg[c4*4 + cc];
          s = fmaf(th[4*cc+0], vv.x, s);
          s = fmaf(th[4*cc+1], vv.y, s);
          s = fmaf(th[4*cc+2], vv.z, s);
          s = fmaf(th[4*cc+3], vv.w, s);
        }
      }
      s += __shfl_xor(s, 1);
      s += __shfl_xor(s, 2);
      if (grp == 0) u_s[j] = s;
    } else if (wid == 15 && i + 1 < NN){
      const int nb = (i + 1) & 1;
      g2_s[nb][lane]      = jax_gumbel(sk0[i+1], sk1[i+1], (uint32_t)(b*NN + lane));
      g2_s[nb][64 + lane] = jax_gumbel(sk0[i+1], sk1[i+1], (uint32_t)(b*NN + 64 + lane));
    }
    __syncthreads();
    float l0 = 0.f, l1 = 0.f; int bi = 0;
    if (wid == 0){
      l0 = 10.0f * fast_tanhf(u_s[lane]);
      l1 = 10.0f * fast_tanhf(u_s[64 + lane]);
      if (mask_s[lane])      l0 = NEG_INF;
      if (mask_s[64 + lane]) l1 = NEG_INF;
      const float y0 = l0 + g2_s[i & 1][lane];
      const float y1 = l1 + g2_s[i & 1][64 + lane];
      float bv;
      if (y1 > y0){ bv = y1; bi = 64 + lane; } else { bv = y0; bi = lane; }
      #pragma unroll
      for (int off = 1; off < 64; off <<= 1){
        const float ov = __shfl_xor(bv, off);
        const int   oi = __shfl_xor(bi, off);
        if (ov > bv || (ov == bv && oi < bi)){ bv = ov; bi = oi; }
      }
      if (i == 0 && id0 == 0) bi = 0;
      if (lane == 0) idx_sh = bi;
    }
    __syncthreads();
    const int idx = idx_sh;
    if (i == 0){
      if (tid < HH){
        const float* arow = lcv + ((size_t)b*NN + idx)*EE;
        float acc = 0.f;
        for (int e = 0; e < EE; ++e) acc = fmaf(arow[e], T1[(size_t)e*HH + tid], acc);
        p1row[tid] = acc;
      }
      __syncthreads();
    }
    if (wid == (idx >> 3)){
      const int r2 = idx & 7;
      float4 pp;
      switch (r2){
        case 0: pp = p2acc[0]; break;
        case 1: pp = p2acc[1]; break;
        case 2: pp = p2acc[2]; break;
        case 3: pp = p2acc[3]; break;
        case 4: pp = p2acc[4]; break;
        case 5: pp = p2acc[5]; break;
        case 6: pp = p2acc[6]; break;
        default: pp = p2acc[7]; break;
      }
      const float4 b4 = ((const float4*)base_s)[lane];
      const float4 p4 = ((const float4*)p1row)[lane];
      float4 nq;
      nq.x = (b4.x + p4.x) + pp.x;
      nq.y = (b4.y + p4.y) + pp.y;
      nq.z = (b4.z + p4.z) + pp.z;
      nq.w = (b4.w + p4.w) + pp.w;
      ((float4*)q_s)[((lane >> 4)*17) + (lane & 15)] = nq;
    }
    if (wid == 0){
      float es = __expf(l0) + __expf(l1);
      #pragma unroll
      for (int off = 1; off < 64; off <<= 1) es += __shfl_xor(es, off);
      const float lown = (bi >= 64) ? l1 : l0;
      const float lsel = __shfl(lown, bi & 63);
      const float logp = lsel - __logf(es);
      if (lane == 0){
        out[OFF_LOGP + b*NN + i] = logp;
        out[OFF_IDX  + b*NN + i] = (float)bi;
        const float2 pc = on_s[cur];
        const float2 pn = on_s[bi];
        const float dx = pn.x - pc.x, dy = pn.y - pc.y;
        out[OFF_RS + b*NN + i] = sqrtf(dx*dx + dy*dy);
        if (i == NN-1){ out[OFF_LAST + 2*b] = pn.x; out[OFF_LAST + 2*b + 1] = pn.y; }
        cur = bi;
        if (mask_s[bi] == 0){
          mask_s[bi] = 1;
          const int p = pos_s[bi];
          const int Lm = L_sh - 1;
          const int last = act_s[Lm];
          act_s[p] = last;
          pos_s[last] = p;
          L_sh = Lm;
        }
      }
    }
  }
}

extern "C" void kernel_launch(void* const* d_in, const int* in_sizes, int n_in,
                              void* d_out, int out_size, void* d_ws, size_t ws_size,
                              hipStream_t stream){
  const float* lcv   = (const float*)d_in[0];
  const float* onode = (const float*)d_in[1];
  const int*   mask  = (const int*)d_in[2];
  const int*   id    = (const int*)d_in[3];
  const float* liw   = (const float*)d_in[4];
  const float* Whbar = (const float*)d_in[5];
  const float* bhbar = (const float*)d_in[6];
  const float* Wrest = (const float*)d_in[7];
  const float* brest = (const float*)d_in[8];
  const float* Wk    = (const float*)d_in[9];
  const float* bk    = (const float*)d_in[10];
  const float* Wq    = (const float*)d_in[11];
  const float* bq    = (const float*)d_in[12];
  const float* vv    = (const float*)d_in[13];

  float* ws  = (float*)d_ws;
  float* out = (float*)d_out;

  const size_t NEED_BYTES = 21267200ull * 4ull;   // 81.1 MB

  if (ws_size >= NEED_BYTES){
    float* T1   = ws;                 // 131072
    float* base = ws + 131072;        // 65536
    float* c0   = ws + 196864;        // 256
    float* qb   = ws + 197120;        // 65536
    float* keys = ws + 262912;        // 8388608
    float* P2   = ws + 8651520;       // 8388608
    float* ltab = ws + 17040128;      // 4227072

    hipLaunchKernelGGL(k_pre,    dim3(769),  dim3(256),  0, stream,
                       liw, Wrest, Wq, lcv, Whbar, bhbar, brest, bq, c0, T1, base);
    hipLaunchKernelGGL(k_keysP2, dim3(256),  dim3(1024), 0, stream,
                       lcv, Wk, T1, bk, base, c0, vv, keys, P2, ltab);
    hipLaunchKernelGGL(k_idx0qb, dim3(256),  dim3(256),  0, stream,
                       ltab, mask, id, lcv, T1, base, qb);
    hipLaunchKernelGGL(k_tab,    dim3(1024), dim3(256),  0, stream, keys, P2, qb, vv, ltab);
    hipLaunchKernelGGL(k_seq,    dim3(256),  dim3(256),  0, stream, ltab, onode, mask, id, out);
  } else {
    // fallback: round-4 path (known-pass)
    float* T1   = ws;            // 512*256
    float* base = ws + 131072;   // 256*256
    float* tmp1 = ws + 196608;   // 256

    hipLaunchKernelGGL(k_tmp1, dim3(1),   dim3(256), 0, stream, liw, Wrest, tmp1);
    hipLaunchKernelGGL(k_T1,   dim3(512), dim3(256), 0, stream, Wrest, Wq, T1);
    hipLaunchKernelGGL(k_base, dim3(256), dim3(256), 0, stream, lcv, Whbar, bhbar, brest, Wq, bq, base);
    hipLaunchKernelGGL(dec_main, dim3(256), dim3(1024), 0, stream,
                       lcv, onode, mask, id, Wk, bk, vv, T1, base, tmp1, Wq, out);
  }
}